// Round 2
// baseline (820.252 us; speedup 1.0000x reference)
//
#include <hip/hip_runtime.h>

typedef unsigned short u16;
typedef __attribute__((ext_vector_type(8))) short bf16x8;   // 8 bf16 = 4 VGPRs
typedef __attribute__((ext_vector_type(4))) float f32x4;

__device__ __forceinline__ float bf2f(u16 u) {
    return __uint_as_float(((unsigned)u) << 16);
}
__device__ __forceinline__ u16 f2bf(float f) {          // RNE (outputs)
    unsigned u = __float_as_uint(f);
    u = (u + 0x7fffu + ((u >> 16) & 1u)) >> 16;
    return (u16)u;
}
__device__ __forceinline__ u16 f2bf_fast(float f) {     // RN w/o tie fix (P only)
    return (u16)((__float_as_uint(f) + 0x8000u) >> 16);
}
__device__ __forceinline__ float fexp2(float x) { return __builtin_amdgcn_exp2f(x); }
__device__ __forceinline__ void gld_lds16(const u16* g, u16* l) {
    __builtin_amdgcn_global_load_lds(
        (const __attribute__((address_space(1))) void*)g,
        (__attribute__((address_space(3))) void*)l, 16, 0, 0);
}
__device__ __forceinline__ unsigned lds_off(const u16* p) {
    return (unsigned)(unsigned long long)(const __attribute__((address_space(3))) u16*)p;
}
__device__ __forceinline__ void barrier_() {
    asm volatile("" ::: "memory");
    __builtin_amdgcn_s_barrier();
    asm volatile("" ::: "memory");
}
#define VMCNT(n) asm volatile("s_waitcnt vmcnt(" #n ")" ::: "memory")
// rule 18: lgkmcnt via asm MUST be followed by sched_barrier(0) so register-only
// MFMAs can't be hoisted above the wait.
#define LGKM0() do { \
    asm volatile("s_waitcnt lgkmcnt(0)" ::: "memory"); \
    __builtin_amdgcn_sched_barrier(0); \
} while(0)
// inline-asm ds_read_b128: keeps the fragment reads out of the compiler's
// alias/waitcnt bookkeeping (counted waits stay OURS, not auto-derived).
#define DSR(dst, addr) asm volatile("ds_read_b128 %0, %1" : "=v"(dst) : "v"(addr))

// ---------------------------------------------------------------------------
// convert: f32 -> bf16, 4 elems/thread.
// ---------------------------------------------------------------------------
__global__ __launch_bounds__(256) void convert_f32_bf16(
    const float* __restrict__ in, u16* __restrict__ out) {
    long i = ((long)blockIdx.x * 256 + threadIdx.x) * 4;
    float4 v = *(const float4*)&in[i];
    alignas(8) u16 o[4] = {f2bf(v.x), f2bf(v.y), f2bf(v.z), f2bf(v.w)};
    *(uint2*)&out[i] = *(const uint2*)o;
}

// f32 copy (residual pre-seed for split-K atomics), 4 elems/thread.
__global__ __launch_bounds__(256) void copy_f32(
    const float* __restrict__ in, float* __restrict__ out) {
    long i = ((long)blockIdx.x * 256 + threadIdx.x) * 4;
    *(float4*)&out[i] = *(const float4*)&in[i];
}

// ---------------------------------------------------------------------------
// Weight transpose + downcast: f32 [R][C] -> bf16 [C][R], 64x64 tiles.
// ---------------------------------------------------------------------------
__device__ __forceinline__ void transpose_w_body(
    const float* __restrict__ in, u16* __restrict__ out, int R, int C) {
    __shared__ u16 tile[64][72];
    int r0 = blockIdx.y * 64, c0 = blockIdx.x * 64;
    int tid = threadIdx.x;
#pragma unroll
    for (int it = 0; it < 4; ++it) {
        int f = it * 1024 + tid * 4;
        int r = f >> 6, c = f & 63;
        float4 v = *(const float4*)&in[(long)(r0 + r) * C + (c0 + c)];
        alignas(8) u16 o[4] = {f2bf(v.x), f2bf(v.y), f2bf(v.z), f2bf(v.w)};
        *(uint2*)&tile[r][c] = *(const uint2*)o;
    }
    __syncthreads();
#pragma unroll
    for (int it = 0; it < 2; ++it) {
        int f = it * 2048 + tid * 8;
        int rr = f >> 6, cc = f & 63;
        alignas(16) u16 tmp[8];
#pragma unroll
        for (int i = 0; i < 8; ++i) tmp[i] = tile[cc + i][rr];
        *(uint4*)&out[(long)(c0 + rr) * R + (r0 + cc)] = *(const uint4*)tmp;
    }
}

__global__ __launch_bounds__(256) void transpose_w(
    const float* __restrict__ in, u16* __restrict__ out, int R, int C) {
    transpose_w_body(in, out, R, C);
}

// 4 batched 1024x1024 transposes (QKVO weights), z selects matrix.
__global__ __launch_bounds__(256) void transpose_w4(
    const float* __restrict__ p0, const float* __restrict__ p1,
    const float* __restrict__ p2, const float* __restrict__ p3,
    u16* __restrict__ out) {
    int z = blockIdx.z;
    const float* in = (z == 0) ? p0 : (z == 1) ? p1 : (z == 2) ? p2 : p3;
    transpose_w_body(in, out + (long)z * 1024 * 1024, 1024, 1024);
}

// ---------------------------------------------------------------------------
// bf16 transpose (for V), input row-stride istride, batched via blockIdx.z.
// ---------------------------------------------------------------------------
__global__ __launch_bounds__(256) void transpose_b(
    const u16* __restrict__ in, u16* __restrict__ out,
    int R, int C, int istride, long ibs, long obs) {
    __shared__ u16 tile[64][72];
    const u16* src = in + (long)blockIdx.z * ibs;
    u16* dst = out + (long)blockIdx.z * obs;
    int r0 = blockIdx.y * 64, c0 = blockIdx.x * 64;
    int tid = threadIdx.x;
#pragma unroll
    for (int it = 0; it < 2; ++it) {
        int f = it * 2048 + tid * 8;
        int r = f >> 6, c = f & 63;
        *(uint4*)&tile[r][c] = *(const uint4*)&src[(long)(r0 + r) * istride + (c0 + c)];
    }
    __syncthreads();
#pragma unroll
    for (int it = 0; it < 2; ++it) {
        int f = it * 2048 + tid * 8;
        int rr = f >> 6, cc = f & 63;
        alignas(16) u16 tmp[8];
#pragma unroll
        for (int i = 0; i < 8; ++i) tmp[i] = tile[cc + i][rr];
        *(uint4*)&dst[(long)(c0 + rr) * R + (r0 + cc)] = *(const uint4*)tmp;
    }
}

// ---------------------------------------------------------------------------
// LayerNorm rows of 1024: f32 in, f32 gamma/beta, bf16 out. One block/row.
// ---------------------------------------------------------------------------
__global__ __launch_bounds__(256) void ln_kernel(
    const float* __restrict__ x, const float* __restrict__ g,
    const float* __restrict__ bta, u16* __restrict__ y) {
    long row = blockIdx.x;
    int tid = threadIdx.x;
    float4 v4 = *(const float4*)&x[row * 1024 + tid * 4];
    float v[4] = {v4.x, v4.y, v4.z, v4.w};
    float s = 0.f, ss = 0.f;
#pragma unroll
    for (int i = 0; i < 4; ++i) { s += v[i]; ss += v[i] * v[i]; }
#pragma unroll
    for (int o = 1; o < 64; o <<= 1) { s += __shfl_xor(s, o, 64); ss += __shfl_xor(ss, o, 64); }
    __shared__ float red[8];
    int wv = tid >> 6, lane = tid & 63;
    if (lane == 0) { red[wv] = s; red[4 + wv] = ss; }
    __syncthreads();
    s = red[0] + red[1] + red[2] + red[3];
    ss = red[4] + red[5] + red[6] + red[7];
    float mean = s * (1.f / 1024.f);
    float var = ss * (1.f / 1024.f) - mean * mean;
    float rs = rsqrtf(var + 1e-5f);
    float4 g4 = *(const float4*)&g[tid * 4];
    float4 b4 = *(const float4*)&bta[tid * 4];
    float gg[4] = {g4.x, g4.y, g4.z, g4.w};
    float bb[4] = {b4.x, b4.y, b4.z, b4.w};
    alignas(8) u16 o4[4];
#pragma unroll
    for (int i = 0; i < 4; ++i)
        o4[i] = f2bf((v[i] - mean) * rs * gg[i] + bb[i]);
    *(uint2*)&y[row * 1024 + tid * 4] = *(const uint2*)o4;
}

// ---------------------------------------------------------------------------
// 256x256 8-phase GEMM (T2+T3+T4+T5), derived-waits port:
// fragment reads are inline-asm ds_read_b128; phase body is exactly
//   {reads | stage} -> s_barrier -> lgkmcnt(0)+sched_barrier -> MFMA -> s_barrier
// vmcnt(4) only at phases 4/8 (2 half-tiles left in flight). LDS swizzle
// slot^=(row&7) applied as inverse-swizzled global source + swizzled read.
// ---------------------------------------------------------------------------
#define STA(b,t,h) do { \
    gld_lds16(Ag + ((h)*128 +  0) * (long)K + (t)*64, AsL + (b)*16384 + (h)*8192); \
    gld_lds16(Ag + ((h)*128 + 64) * (long)K + (t)*64, AsL + (b)*16384 + (h)*8192 + 4096); \
} while(0)
#define STB(b,t,h) do { \
    gld_lds16(Bg + ((h)*128 +  0) * (long)K + (t)*64, BsL + (b)*16384 + (h)*8192); \
    gld_lds16(Bg + ((h)*128 + 64) * (long)K + (t)*64, BsL + (b)*16384 + (h)*8192 + 4096); \
} while(0)
// byte offsets: buffer b -> b*32768, row r -> r*2048 (64 u16 * 2B * swizzle-safe)
#define RDB(b) do { \
    DSR(bfr[0][0], aB0 + (b)*32768 +    0); DSR(bfr[0][1], aB1 + (b)*32768 +    0); \
    DSR(bfr[1][0], aB0 + (b)*32768 + 2048); DSR(bfr[1][1], aB1 + (b)*32768 + 2048); \
    DSR(bfr[2][0], aB0 + (b)*32768 + 4096); DSR(bfr[2][1], aB1 + (b)*32768 + 4096); \
    DSR(bfr[3][0], aB0 + (b)*32768 + 6144); DSR(bfr[3][1], aB1 + (b)*32768 + 6144); \
} while(0)
#define RDA(b,q) do { \
    DSR(a0, aA0 + (b)*32768 + (2*(q)  )*2048); \
    DSR(a1, aA1 + (b)*32768 + (2*(q)  )*2048); \
    DSR(a2, aA0 + (b)*32768 + (2*(q)+1)*2048); \
    DSR(a3, aA1 + (b)*32768 + (2*(q)+1)*2048); \
} while(0)
#define MM(q) do { \
    __builtin_amdgcn_s_setprio(1); \
    _Pragma("unroll") \
    for (int j = 0; j < 4; ++j) { \
        acc[2*(q)  ][j] = __builtin_amdgcn_mfma_f32_16x16x32_bf16(a0, bfr[j][0], acc[2*(q)  ][j], 0, 0, 0); \
        acc[2*(q)  ][j] = __builtin_amdgcn_mfma_f32_16x16x32_bf16(a1, bfr[j][1], acc[2*(q)  ][j], 0, 0, 0); \
        acc[2*(q)+1][j] = __builtin_amdgcn_mfma_f32_16x16x32_bf16(a2, bfr[j][0], acc[2*(q)+1][j], 0, 0, 0); \
        acc[2*(q)+1][j] = __builtin_amdgcn_mfma_f32_16x16x32_bf16(a3, bfr[j][1], acc[2*(q)+1][j], 0, 0, 0); } \
    __builtin_amdgcn_s_setprio(0); \
} while(0)

template<int BIAS, int RES, int RELU, int OUTF32, int SPLITK>
__device__ __forceinline__ void gemm256_body(
    const u16* __restrict__ A, const u16* __restrict__ Bt,
    const float* __restrict__ bias, const float* __restrict__ res,
    void* __restrict__ Cv, long bm, long bn, int K, int kLen, int koff,
    int ldc, int kz, u16* As, u16* Bs) {
    int tid = threadIdx.x;
    int lane = tid & 63;
    int l15 = lane & 15, quad = lane >> 4;
    int wv = tid >> 6, wm = wv >> 2, wn = wv & 3;
    int NT = kLen >> 6, NI = NT >> 1;

    // staging addresses (linear LDS dest, inverse-swizzled global source)
    int srow = tid >> 3;                                // 0..63
    int scol = ((tid & 7) ^ (srow & 7)) << 3;           // u16 elems
    const u16* Ag = A + (bm + srow) * (long)K + koff + scol;
    const u16* Bg = Bt + (bn + srow) * (long)K + koff + scol;
    u16* AsL = As + tid * 8;
    u16* BsL = Bs + tid * 8;

    // fragment read addresses (swizzled), as 32-bit LDS byte addresses
    int c0 = (quad * 8) ^ ((l15 & 7) << 3);
    int c1 = (32 + quad * 8) ^ ((l15 & 7) << 3);
    unsigned arB = lds_off(As + (wm * 128 + l15) * 64);
    unsigned brB = lds_off(Bs + (wn * 64 + l15) * 64);
    unsigned aA0 = arB + 2 * c0, aA1 = arB + 2 * c1;
    unsigned aB0 = brB + 2 * c0, aB1 = brB + 2 * c1;

    f32x4 zf = {0.f, 0.f, 0.f, 0.f};
    f32x4 acc[8][4];
#pragma unroll
    for (int i = 0; i < 8; ++i)
#pragma unroll
        for (int j = 0; j < 4; ++j) acc[i][j] = zf;

    // prologue: tile0 {A0,A1,B0,B1}, tile1 {B0,B1}; wait tile0 (leave t1.B)
    STA(0,0,0); STA(0,0,1); STB(0,0,0); STB(0,0,1); STB(1,1,0); STB(1,1,1);
    VMCNT(4);
    barrier_();

    bf16x8 bfr[4][2];
    bf16x8 a0, a1, a2, a3;

#pragma unroll 1
    for (int it2 = 0; it2 < NI; ++it2) {
        int t = 2 * it2, t1 = t + 1;
        int ts2 = (t + 2 < NT) ? t + 2 : t;       // even -> buf0
        int ts3 = (t + 3 < NT) ? t + 3 : t1;      // odd  -> buf1
        // ---- tile t (buf0) ----
        RDB(0); RDA(0,0); STA(1,t1,0);            barrier_(); LGKM0(); MM(0); barrier_();
        RDA(0,1);         STA(1,t1,1);            barrier_(); LGKM0(); MM(1); barrier_();
        RDA(0,2);         STB(0,ts2,0);           barrier_(); LGKM0(); MM(2); barrier_();
        RDA(0,3);         STB(0,ts2,1); VMCNT(4); barrier_(); LGKM0(); MM(3); barrier_();
        // ---- tile t+1 (buf1) ----
        RDB(1); RDA(1,0); STA(0,ts2,0);           barrier_(); LGKM0(); MM(0); barrier_();
        RDA(1,1);         STA(0,ts2,1);           barrier_(); LGKM0(); MM(1); barrier_();
        RDA(1,2);         STB(1,ts3,0);           barrier_(); LGKM0(); MM(2); barrier_();
        RDA(1,3);         STB(1,ts3,1); VMCNT(4); barrier_(); LGKM0(); MM(3); barrier_();
    }
    VMCNT(0);   // drain in-flight LDS DMA before workgroup exit

    // epilogue
    long row0 = bm + wm * 128 + quad * 4;
    long col0 = bn + wn * 64 + l15;
#pragma unroll
    for (int i = 0; i < 8; ++i) {
        long row = row0 + i * 16;
#pragma unroll
        for (int j = 0; j < 4; ++j) {
            long col = col0 + j * 16;
            float bv = (BIAS && (!SPLITK || kz == 0)) ? bias[col] : 0.f;
#pragma unroll
            for (int r = 0; r < 4; ++r) {
                float v = acc[i][j][r] + bv;
                if (RES) v += res[(row + r) * ldc + col];
                if (RELU) v = fmaxf(v, 0.f);
                if (SPLITK) atomicAdd(&((float*)Cv)[(row + r) * ldc + col], v);
                else if (OUTF32) ((float*)Cv)[(row + r) * ldc + col] = v;
                else ((u16*)Cv)[(row + r) * ldc + col] = f2bf(v);
            }
        }
    }
}

template<int BIAS, int RES, int RELU, int OUTF32, int SPLITK>
__global__ __launch_bounds__(512) void gemm256(
    const u16* __restrict__ A, const u16* __restrict__ Bt,
    const float* __restrict__ bias, const float* __restrict__ res,
    void* __restrict__ Cv, int tilesM, int K, int ldc) {
    __shared__ u16 As[2 * 256 * 64];
    __shared__ u16 Bs[2 * 256 * 64];
    int id = blockIdx.x;
    long bm = (long)(id % tilesM) * 256, bn = (long)(id / tilesM) * 256;
    int kLen = SPLITK ? (K >> 1) : K;
    int koff = SPLITK ? ((int)blockIdx.y * kLen) : 0;
    gemm256_body<BIAS, RES, RELU, OUTF32, SPLITK>(
        A, Bt, bias, res, Cv, bm, bn, K, kLen, koff, ldc, blockIdx.y, As, Bs);
}

// Merged cross-attention projections, one 384-block dispatch:
//   id <  128: qbuf[8192,1024] = hq @ wT[0]^T
//   id >= 128: kv [8192,2048] = encb @ wT[1..2]^T
__global__ __launch_bounds__(512) void gemm256_cross(
    const u16* __restrict__ hq, const u16* __restrict__ encb,
    const u16* __restrict__ wT, u16* __restrict__ qbuf, u16* __restrict__ kv) {
    __shared__ u16 As[2 * 256 * 64];
    __shared__ u16 Bs[2 * 256 * 64];
    int id = blockIdx.x;
    const u16* A; const u16* Bt; u16* C; int ldc;
    if (id < 128) { A = hq; Bt = wT; C = qbuf; ldc = 1024; }
    else { id -= 128; A = encb; Bt = wT + 1024l * 1024l; C = kv; ldc = 2048; }
    long bm = (long)(id % 32) * 256, bn = (long)(id / 32) * 256;
    gemm256_body<0, 0, 0, 0, 0>(
        A, Bt, nullptr, nullptr, C, bm, bn, 1024, 1024, 0, ldc, 0, As, Bs);
}

// ---------------------------------------------------------------------------
// Flash attention (bf16). Grid (T/64, H, B); 4 waves x 16 Q rows.
// q/k row strides qld/kld (fused-QKV layouts); vT: [B][H][64][S]; out ld 1024.
// Wave-shared running max; deferred l reduction; exp2 w/ folded 1/8 scale.
// ---------------------------------------------------------------------------
template<bool CAUSAL>
__global__ __launch_bounds__(256) void attn_kernel(
    const u16* __restrict__ q, const u16* __restrict__ k,
    const u16* __restrict__ vT, u16* __restrict__ out, int qld, int kld) {
    __shared__ u16 Qs[64][72];
    __shared__ u16 Ks[64][72];
    __shared__ u16 VTs[64][72];
    __shared__ u16 Ps[4][16][72];
    const int S_ = 1024;
    int qt = CAUSAL ? (gridDim.x - 1 - blockIdx.x) : blockIdx.x;
    int h = blockIdx.y, b = blockIdx.z;
    int tid = threadIdx.x, lane = tid & 63, wv = tid >> 6;
    int l15 = lane & 15, quad = lane >> 4;
    long qbase = ((long)b * 1024 + qt * 64) * qld + h * 64;
    long obase = ((long)b * 1024 + qt * 64) * 1024 + h * 64;
#pragma unroll
    for (int it = 0; it < 2; ++it) {
        int f = it * 2048 + tid * 8;
        int r = f >> 6, c = f & 63;
        *(uint4*)&Qs[r][c] = *(const uint4*)&q[qbase + (long)r * qld + c];
    }
    __syncthreads();
    bf16x8 a0 = *(const bf16x8*)&Qs[wv * 16 + l15][quad * 8];
    bf16x8 a1 = *(const bf16x8*)&Qs[wv * 16 + l15][quad * 8 + 32];
    f32x4 zf = {0.f, 0.f, 0.f, 0.f};
    f32x4 O[4];
#pragma unroll
    for (int j = 0; j < 4; ++j) O[j] = zf;
    const float cs = 0.125f * 1.44269504089f;   // fold 1/sqrt(64) into exp2
    float m_run = -3e30f;                       // wave-shared (16 rows)
    float lp[4] = {0.f, 0.f, 0.f, 0.f};        // per-lane partial l
    long kbase = (long)b * 1024 * kld + h * 64;
    long vtbase = ((long)b * 16 + h) * 64 * (long)S_;
    int ktmax = CAUSAL ? qt : (S_ / 64 - 1);

    for (int kt = 0; kt <= ktmax; ++kt) {
        __syncthreads();
#pragma unroll
        for (int it = 0; it < 2; ++it) {
            int f = it * 2048 + tid * 8;
            int r = f >> 6, c = f & 63;
            *(uint4*)&Ks[r][c]  = *(const uint4*)&k[kbase + (long)(kt * 64 + r) * kld + c];
            *(uint4*)&VTs[r][c] = *(const uint4*)&vT[vtbase + (long)r * S_ + kt * 64 + c];
        }
        __syncthreads();

        f32x4 s[4];
#pragma unroll
        for (int j = 0; j < 4; ++j) {
            bf16x8 kb0 = *(const bf16x8*)&Ks[j * 16 + l15][quad * 8];
            bf16x8 kb1 = *(const bf16x8*)&Ks[j * 16 + l15][quad * 8 + 32];
            f32x4 z = zf;
            z = __builtin_amdgcn_mfma_f32_16x16x32_bf16(a0, kb0, z, 0, 0, 0);
            z = __builtin_amdgcn_mfma_f32_16x16x32_bf16(a1, kb1, z, 0, 0, 0);
            s[j] = z;
        }
        if (CAUSAL && kt == qt) {
#pragma unroll
            for (int j = 0; j < 4; ++j)
#pragma unroll
                for (int r = 0; r < 4; ++r)
                    if ((j * 16 + l15) > (wv * 16 + quad * 4 + r)) s[j][r] = -3e30f;
        }
        float mx = s[0][0];
#pragma unroll
        for (int j = 0; j < 4; ++j)
#pragma unroll
            for (int r = 0; r < 4; ++r) mx = fmaxf(mx, s[j][r]);
#pragma unroll
        for (int o = 1; o < 64; o <<= 1) mx = fmaxf(mx, __shfl_xor(mx, o, 64));
        float mn = fmaxf(m_run, mx);
        bool grew = mn > m_run;
        if (grew) {
            float alpha = fexp2((m_run - mn) * cs);
            m_run = mn;
#pragma unroll
            for (int j = 0; j < 4; ++j) {
                O[j][0] *= alpha; O[j][1] *= alpha; O[j][2] *= alpha; O[j][3] *= alpha;
            }
#pragma unroll
            for (int r = 0; r < 4; ++r) lp[r] *= alpha;
        }
        float mc = m_run * cs;
#pragma unroll
        for (int j = 0; j < 4; ++j)
#pragma unroll
            for (int r = 0; r < 4; ++r) {
                float p = fexp2(__builtin_fmaf(s[j][r], cs, -mc));
                lp[r] += p;
                Ps[wv][quad * 4 + r][j * 16 + l15] = f2bf_fast(p);
            }
        bf16x8 pa0 = *(const bf16x8*)&Ps[wv][l15][quad * 8];
        bf16x8 pa1 = *(const bf16x8*)&Ps[wv][l15][quad * 8 + 32];
#pragma unroll
        for (int j = 0; j < 4; ++j) {
            bf16x8 vb0 = *(const bf16x8*)&VTs[j * 16 + l15][quad * 8];
            bf16x8 vb1 = *(const bf16x8*)&VTs[j * 16 + l15][quad * 8 + 32];
            f32x4 o = O[j];
            o = __builtin_amdgcn_mfma_f32_16x16x32_bf16(pa0, vb0, o, 0, 0, 0);
            o = __builtin_amdgcn_mfma_f32_16x16x32_bf16(pa1, vb1, o, 0, 0, 0);
            O[j] = o;
        }
    }
#pragma unroll
    for (int r = 0; r < 4; ++r) {
#pragma unroll
        for (int o = 1; o < 16; o <<= 1) lp[r] += __shfl_xor(lp[r], o, 64);
        lp[r] = 1.f / lp[r];
    }
#pragma unroll
    for (int j = 0; j < 4; ++j)
#pragma unroll
        for (int r = 0; r < 4; ++r)
            out[obase + (long)(wv * 16 + quad * 4 + r) * 1024 + j * 16 + l15] =
                f2bf(O[j][r] * lp[r]);
}

// ---------------------------------------------------------------------------
// Workspace (u16 units; MEG = 1M; total 60 MEG = 120 MB):
//   0- 8 hbuf | 8-32 qkv (self) / cross: qbuf(8-16)+kv(16-32)
//  32-40 vTb / encb (encb dies before vTb written)
//  40-43 wT (q|k|v transposed, contiguous) | 43-44 wT3 (o)
//  44-60 x1 (f32); FFN: w1T 44-48, w2T 48-52 (x1 dead), ff1 8-40
//  Output projections + FFN2 are split-K=2 with f32 atomicAdd; the residual
//  is pre-seeded into the destination by copy_f32 (replaces the res-read).
// ---------------------------------------------------------------------------
extern "C" void kernel_launch(void* const* d_in, const int* in_sizes, int n_in,
                              void* d_out, int out_size, void* d_ws, size_t ws_size,
                              hipStream_t stream) {
    (void)in_sizes; (void)n_in; (void)out_size; (void)ws_size;
    const float* x    = (const float*)d_in[0];
    const float* enc  = (const float*)d_in[1];
    // d_in[2]=tgt_mask, d_in[3]=src_mask: all-true; causal applied explicitly
    const float* ln1g = (const float*)d_in[4];
    const float* ln1b = (const float*)d_in[5];
    const float* ln2g = (const float*)d_in[6];
    const float* ln2b = (const float*)d_in[7];
    const float* ln3g = (const float*)d_in[8];
    const float* ln3b = (const float*)d_in[9];
    const float* Wq_s = (const float*)d_in[10];
    const float* Wk_s = (const float*)d_in[11];
    const float* Wv_s = (const float*)d_in[12];
    const float* Wo_s = (const float*)d_in[13];
    const float* bo_s = (const float*)d_in[14];
    const float* Wq_c = (const float*)d_in[15];
    const float* Wk_c = (const float*)d_in[16];
    const float* Wv_c = (const float*)d_in[17];
    const float* Wo_c = (const float*)d_in[18];
    const float* bo_c = (const float*)d_in[19];
    const float* W1   = (const float*)d_in[20];
    const float* b1   = (const float*)d_in[21];
    const float* W2   = (const float*)d_in[22];
    const float* b2   = (const float*)d_in[23];
    float* out = (float*)d_out;

    const long MEG = 1024l * 1024l;
    u16* ws0  = (u16*)d_ws;
    u16* hbuf = ws0 + 0 * MEG;
    u16* qkv  = ws0 + 8 * MEG;            // self: [8192][3072]
    u16* qbuf = ws0 + 8 * MEG;            // cross: [8192][1024]
    u16* kv   = ws0 + 16 * MEG;           // cross: [8192][2048]
    u16* vTb  = ws0 + 32 * MEG;
    u16* encb = ws0 + 32 * MEG;           // dead before vTb is written
    u16* wT   = ws0 + 40 * MEG;           // 3 contiguous MEG: q|k|v transposed
    u16* wT3  = ws0 + 43 * MEG;
    float* x1 = (float*)(ws0 + 44 * MEG); // 8M f32
    u16* ff1  = qkv;                      // 8-40 MEG after attention buffers die
    u16* w1T  = ws0 + 44 * MEG;           // after x1 dies
    u16* w2T  = ws0 + 48 * MEG;

    dim3 blk(256);
    dim3 blk5(512);
    dim3 gW4(16, 16, 4);      // batched 4x 1024^2 weight transpose
    dim3 gA(16, 16, 8);       // attention / batched v-transpose

    // ---- self attention ----
    transpose_w4<<<gW4, blk, 0, stream>>>(Wq_s, Wk_s, Wv_s, Wo_s, wT);  // wT3=wT+3M
    ln_kernel<<<8192, blk, 0, stream>>>(x, ln1g, ln1b, hbuf);
    gemm256<0,0,0,0,0><<<384, blk5, 0, stream>>>(hbuf, wT, nullptr, nullptr, qkv, 32, 1024, 3072);
    transpose_b<<<gA, blk, 0, stream>>>(qkv + 2048, vTb, 1024, 1024, 3072, 1024l * 3072, MEG);
    attn_kernel<true><<<gA, blk, 0, stream>>>(qkv, qkv + 1024, vTb, hbuf, 3072, 3072);
    copy_f32<<<8192, blk, 0, stream>>>(x, x1);   // residual pre-seed
    gemm256<1,0,0,1,1><<<dim3(128, 2), blk5, 0, stream>>>(hbuf, wT3, bo_s, nullptr, x1, 32, 1024, 1024);

    // ---- cross attention ----
    transpose_w4<<<gW4, blk, 0, stream>>>(Wq_c, Wk_c, Wv_c, Wo_c, wT);
    ln_kernel<<<8192, blk, 0, stream>>>(x1, ln2g, ln2b, hbuf);
    convert_f32_bf16<<<8192, blk, 0, stream>>>(enc, encb);
    gemm256_cross<<<384, blk5, 0, stream>>>(hbuf, encb, wT, qbuf, kv);
    transpose_b<<<gA, blk, 0, stream>>>(kv + 1024, vTb, 1024, 1024, 2048, 1024l * 2048, MEG);  // encb dead
    attn_kernel<false><<<gA, blk, 0, stream>>>(qbuf, kv, vTb, hbuf, 1024, 2048);
    copy_f32<<<8192, blk, 0, stream>>>(x1, out); // residual pre-seed
    gemm256<1,0,0,1,1><<<dim3(128, 2), blk5, 0, stream>>>(hbuf, wT3, bo_c, nullptr, out, 32, 1024, 1024);

    // ---- FFN (x1 dead; w1T/w2T reuse its slot) ----
    transpose_w<<<dim3(64, 16, 1), blk, 0, stream>>>(W1, w1T, 1024, 4096);
    transpose_w<<<dim3(16, 64, 1), blk, 0, stream>>>(W2, w2T, 4096, 1024);
    ln_kernel<<<8192, blk, 0, stream>>>(out, ln3g, ln3b, hbuf);
    gemm256<1,0,1,0,0><<<512, blk5, 0, stream>>>(hbuf, w1T, b1, nullptr, ff1, 32, 1024, 4096);
    // split-K=2: out already holds x2 (residual); z=0 adds b2.
    gemm256<1,0,0,1,1><<<dim3(128, 2), blk5, 0, stream>>>(ff1, w2T, b2, nullptr, out, 32, 4096, 1024);
}

// Round 3
// 756.885 us; speedup vs baseline: 1.0837x; 1.0837x over previous
//
#include <hip/hip_runtime.h>

typedef unsigned short u16;
typedef __attribute__((ext_vector_type(8))) short bf16x8;   // 8 bf16 = 4 VGPRs
typedef __attribute__((ext_vector_type(4))) float f32x4;

__device__ __forceinline__ float bf2f(u16 u) {
    return __uint_as_float(((unsigned)u) << 16);
}
__device__ __forceinline__ u16 f2bf(float f) {          // RNE (outputs)
    unsigned u = __float_as_uint(f);
    u = (u + 0x7fffu + ((u >> 16) & 1u)) >> 16;
    return (u16)u;
}
__device__ __forceinline__ u16 f2bf_fast(float f) {     // RN w/o tie fix (P only)
    return (u16)((__float_as_uint(f) + 0x8000u) >> 16);
}
__device__ __forceinline__ float fexp2(float x) { return __builtin_amdgcn_exp2f(x); }
__device__ __forceinline__ void gld_lds16(const u16* g, u16* l) {
    __builtin_amdgcn_global_load_lds(
        (const __attribute__((address_space(1))) void*)g,
        (__attribute__((address_space(3))) void*)l, 16, 0, 0);
}
__device__ __forceinline__ unsigned lds_off(const u16* p) {
    return (unsigned)(unsigned long long)(const __attribute__((address_space(3))) u16*)p;
}
__device__ __forceinline__ void barrier_() {
    asm volatile("" ::: "memory");
    __builtin_amdgcn_s_barrier();
    asm volatile("" ::: "memory");
}
#define VMCNT(n) asm volatile("s_waitcnt vmcnt(" #n ")" ::: "memory")
// rule 18: lgkmcnt via asm MUST be followed by sched_barrier(0) so register-only
// MFMAs can't be hoisted above the wait. Counted variants: only our asm
// ds_read_b128 touch lgkmcnt inside the loop (global_load_lds is vmcnt-only).
#define LGKM(n) do { \
    asm volatile("s_waitcnt lgkmcnt(" #n ")" ::: "memory"); \
    __builtin_amdgcn_sched_barrier(0); \
} while(0)
#define DSR(dst, addr) asm volatile("ds_read_b128 %0, %1" : "=v"(dst) : "v"(addr))

// ---------------------------------------------------------------------------
// convert: f32 -> bf16, 4 elems/thread.
// ---------------------------------------------------------------------------
__global__ __launch_bounds__(256) void convert_f32_bf16(
    const float* __restrict__ in, u16* __restrict__ out) {
    long i = ((long)blockIdx.x * 256 + threadIdx.x) * 4;
    float4 v = *(const float4*)&in[i];
    alignas(8) u16 o[4] = {f2bf(v.x), f2bf(v.y), f2bf(v.z), f2bf(v.w)};
    *(uint2*)&out[i] = *(const uint2*)o;
}

// ---------------------------------------------------------------------------
// Weight transpose + downcast: f32 [R][C] -> bf16 [C][R], 64x64 tiles.
// ---------------------------------------------------------------------------
__device__ __forceinline__ void transpose_w_body(
    const float* __restrict__ in, u16* __restrict__ out, int R, int C) {
    __shared__ u16 tile[64][72];
    int r0 = blockIdx.y * 64, c0 = blockIdx.x * 64;
    int tid = threadIdx.x;
#pragma unroll
    for (int it = 0; it < 4; ++it) {
        int f = it * 1024 + tid * 4;
        int r = f >> 6, c = f & 63;
        float4 v = *(const float4*)&in[(long)(r0 + r) * C + (c0 + c)];
        alignas(8) u16 o[4] = {f2bf(v.x), f2bf(v.y), f2bf(v.z), f2bf(v.w)};
        *(uint2*)&tile[r][c] = *(const uint2*)o;
    }
    __syncthreads();
#pragma unroll
    for (int it = 0; it < 2; ++it) {
        int f = it * 2048 + tid * 8;
        int rr = f >> 6, cc = f & 63;
        alignas(16) u16 tmp[8];
#pragma unroll
        for (int i = 0; i < 8; ++i) tmp[i] = tile[cc + i][rr];
        *(uint4*)&out[(long)(c0 + rr) * R + (r0 + cc)] = *(const uint4*)tmp;
    }
}

__global__ __launch_bounds__(256) void transpose_w(
    const float* __restrict__ in, u16* __restrict__ out, int R, int C) {
    transpose_w_body(in, out, R, C);
}

// 4 batched 1024x1024 transposes (QKVO weights), z selects matrix.
__global__ __launch_bounds__(256) void transpose_w4(
    const float* __restrict__ p0, const float* __restrict__ p1,
    const float* __restrict__ p2, const float* __restrict__ p3,
    u16* __restrict__ out) {
    int z = blockIdx.z;
    const float* in = (z == 0) ? p0 : (z == 1) ? p1 : (z == 2) ? p2 : p3;
    transpose_w_body(in, out + (long)z * 1024 * 1024, 1024, 1024);
}

// ---------------------------------------------------------------------------
// bf16 transpose (for V), input row-stride istride, batched via blockIdx.z.
// ---------------------------------------------------------------------------
__global__ __launch_bounds__(256) void transpose_b(
    const u16* __restrict__ in, u16* __restrict__ out,
    int R, int C, int istride, long ibs, long obs) {
    __shared__ u16 tile[64][72];
    const u16* src = in + (long)blockIdx.z * ibs;
    u16* dst = out + (long)blockIdx.z * obs;
    int r0 = blockIdx.y * 64, c0 = blockIdx.x * 64;
    int tid = threadIdx.x;
#pragma unroll
    for (int it = 0; it < 2; ++it) {
        int f = it * 2048 + tid * 8;
        int r = f >> 6, c = f & 63;
        *(uint4*)&tile[r][c] = *(const uint4*)&src[(long)(r0 + r) * istride + (c0 + c)];
    }
    __syncthreads();
#pragma unroll
    for (int it = 0; it < 2; ++it) {
        int f = it * 2048 + tid * 8;
        int rr = f >> 6, cc = f & 63;
        alignas(16) u16 tmp[8];
#pragma unroll
        for (int i = 0; i < 8; ++i) tmp[i] = tile[cc + i][rr];
        *(uint4*)&dst[(long)(c0 + rr) * R + (r0 + cc)] = *(const uint4*)tmp;
    }
}

// ---------------------------------------------------------------------------
// LayerNorm rows of 1024: f32 in, f32 gamma/beta, bf16 out. One block/row.
// ---------------------------------------------------------------------------
__global__ __launch_bounds__(256) void ln_kernel(
    const float* __restrict__ x, const float* __restrict__ g,
    const float* __restrict__ bta, u16* __restrict__ y) {
    long row = blockIdx.x;
    int tid = threadIdx.x;
    float4 v4 = *(const float4*)&x[row * 1024 + tid * 4];
    float v[4] = {v4.x, v4.y, v4.z, v4.w};
    float s = 0.f, ss = 0.f;
#pragma unroll
    for (int i = 0; i < 4; ++i) { s += v[i]; ss += v[i] * v[i]; }
#pragma unroll
    for (int o = 1; o < 64; o <<= 1) { s += __shfl_xor(s, o, 64); ss += __shfl_xor(ss, o, 64); }
    __shared__ float red[8];
    int wv = tid >> 6, lane = tid & 63;
    if (lane == 0) { red[wv] = s; red[4 + wv] = ss; }
    __syncthreads();
    s = red[0] + red[1] + red[2] + red[3];
    ss = red[4] + red[5] + red[6] + red[7];
    float mean = s * (1.f / 1024.f);
    float var = ss * (1.f / 1024.f) - mean * mean;
    float rs = rsqrtf(var + 1e-5f);
    float4 g4 = *(const float4*)&g[tid * 4];
    float4 b4 = *(const float4*)&bta[tid * 4];
    float gg[4] = {g4.x, g4.y, g4.z, g4.w};
    float bb[4] = {b4.x, b4.y, b4.z, b4.w};
    alignas(8) u16 o4[4];
#pragma unroll
    for (int i = 0; i < 4; ++i)
        o4[i] = f2bf((v[i] - mean) * rs * gg[i] + bb[i]);
    *(uint2*)&y[row * 1024 + tid * 4] = *(const uint2*)o4;
}

// ---------------------------------------------------------------------------
// 256x256 8-phase GEMM (T2+T3+T4+T5) with pipelined LDS reads + dep-reordered
// MFMA. Per tile (4 phases):
//   p1: RDB + a-set0(q0) + a-set1(q1) reads; stage; bar; lgkm(4);  MM(q0,set0)
//   p2: a-set0(q2) reads;               stage; bar; lgkm(4);  MM(q1,set1)
//   p3: a-set1(q3) reads;               stage; bar; lgkm(4);  MM(q2,set0)
//   p4:                                 stage; bar; lgkm(0);  MM(q3,set1)
// Counted lgkm: phase-p MFMA overlaps service of phase-p+1's reads. lgkm(0)
// at p4/p8 still drains ALL buffer reads before the next stage overwrites it.
// MM issues 8 independent k-half-0 MFMAs then 8 k-half-1 (dep distance 8,
// was 2). Stage order + vmcnt(4)@p4/p8 unchanged (2 half-tiles in flight).
// LDS swizzle slot^=(row&7): inverse-swizzled global src + swizzled read.
// ---------------------------------------------------------------------------
#define STA(b,t,h) do { \
    gld_lds16(Ag + ((h)*128 +  0) * (long)K + (t)*64, AsL + (b)*16384 + (h)*8192); \
    gld_lds16(Ag + ((h)*128 + 64) * (long)K + (t)*64, AsL + (b)*16384 + (h)*8192 + 4096); \
} while(0)
#define STB(b,t,h) do { \
    gld_lds16(Bg + ((h)*128 +  0) * (long)K + (t)*64, BsL + (b)*16384 + (h)*8192); \
    gld_lds16(Bg + ((h)*128 + 64) * (long)K + (t)*64, BsL + (b)*16384 + (h)*8192 + 4096); \
} while(0)
#define RDB(b) do { \
    DSR(bfr[0][0], aB0 + (b)*32768 +    0); DSR(bfr[0][1], aB1 + (b)*32768 +    0); \
    DSR(bfr[1][0], aB0 + (b)*32768 + 2048); DSR(bfr[1][1], aB1 + (b)*32768 + 2048); \
    DSR(bfr[2][0], aB0 + (b)*32768 + 4096); DSR(bfr[2][1], aB1 + (b)*32768 + 4096); \
    DSR(bfr[3][0], aB0 + (b)*32768 + 6144); DSR(bfr[3][1], aB1 + (b)*32768 + 6144); \
} while(0)
// a-fragment read into register set P {pa0..pa3} or Q {pb0..pb3}
#define RDAP(b,q) do { \
    DSR(pa0, aA0 + (b)*32768 + (2*(q)  )*2048); \
    DSR(pa1, aA1 + (b)*32768 + (2*(q)  )*2048); \
    DSR(pa2, aA0 + (b)*32768 + (2*(q)+1)*2048); \
    DSR(pa3, aA1 + (b)*32768 + (2*(q)+1)*2048); \
} while(0)
#define RDAQ(b,q) do { \
    DSR(pb0, aA0 + (b)*32768 + (2*(q)  )*2048); \
    DSR(pb1, aA1 + (b)*32768 + (2*(q)  )*2048); \
    DSR(pb2, aA0 + (b)*32768 + (2*(q)+1)*2048); \
    DSR(pb3, aA1 + (b)*32768 + (2*(q)+1)*2048); \
} while(0)
// dep-reordered MFMA cluster: all k-half-0 first (8 independent), then k-half-1
#define MM(q, A0, A1, A2, A3) do { \
    __builtin_amdgcn_s_setprio(1); \
    _Pragma("unroll") \
    for (int j = 0; j < 4; ++j) \
        acc[2*(q)  ][j] = __builtin_amdgcn_mfma_f32_16x16x32_bf16(A0, bfr[j][0], acc[2*(q)  ][j], 0, 0, 0); \
    _Pragma("unroll") \
    for (int j = 0; j < 4; ++j) \
        acc[2*(q)+1][j] = __builtin_amdgcn_mfma_f32_16x16x32_bf16(A2, bfr[j][0], acc[2*(q)+1][j], 0, 0, 0); \
    _Pragma("unroll") \
    for (int j = 0; j < 4; ++j) \
        acc[2*(q)  ][j] = __builtin_amdgcn_mfma_f32_16x16x32_bf16(A1, bfr[j][1], acc[2*(q)  ][j], 0, 0, 0); \
    _Pragma("unroll") \
    for (int j = 0; j < 4; ++j) \
        acc[2*(q)+1][j] = __builtin_amdgcn_mfma_f32_16x16x32_bf16(A3, bfr[j][1], acc[2*(q)+1][j], 0, 0, 0); \
    __builtin_amdgcn_s_setprio(0); \
} while(0)

template<int BIAS, int RES, int RELU, int OUTF32, int SPLITK>
__device__ __forceinline__ void gemm256_body(
    const u16* __restrict__ A, const u16* __restrict__ Bt,
    const float* __restrict__ bias, const float* __restrict__ res,
    void* __restrict__ Cv, long bm, long bn, int K, int kLen, int koff,
    int ldc, int kz, u16* As, u16* Bs) {
    int tid = threadIdx.x;
    int lane = tid & 63;
    int l15 = lane & 15, quad = lane >> 4;
    int wv = tid >> 6, wm = wv >> 2, wn = wv & 3;
    int NT = kLen >> 6, NI = NT >> 1;

    // staging addresses (linear LDS dest, inverse-swizzled global source)
    int srow = tid >> 3;                                // 0..63
    int scol = ((tid & 7) ^ (srow & 7)) << 3;           // u16 elems
    const u16* Ag = A + (bm + srow) * (long)K + koff + scol;
    const u16* Bg = Bt + (bn + srow) * (long)K + koff + scol;
    u16* AsL = As + tid * 8;
    u16* BsL = Bs + tid * 8;

    // fragment read addresses (swizzled), as 32-bit LDS byte addresses
    int c0 = (quad * 8) ^ ((l15 & 7) << 3);
    int c1 = (32 + quad * 8) ^ ((l15 & 7) << 3);
    unsigned arB = lds_off(As + (wm * 128 + l15) * 64);
    unsigned brB = lds_off(Bs + (wn * 64 + l15) * 64);
    unsigned aA0 = arB + 2 * c0, aA1 = arB + 2 * c1;
    unsigned aB0 = brB + 2 * c0, aB1 = brB + 2 * c1;

    f32x4 zf = {0.f, 0.f, 0.f, 0.f};
    f32x4 acc[8][4];
#pragma unroll
    for (int i = 0; i < 8; ++i)
#pragma unroll
        for (int j = 0; j < 4; ++j) acc[i][j] = zf;

    // prologue: tile0 {A0,A1,B0,B1}, tile1 {B0,B1}; wait tile0 (leave t1.B)
    STA(0,0,0); STA(0,0,1); STB(0,0,0); STB(0,0,1); STB(1,1,0); STB(1,1,1);
    VMCNT(4);
    barrier_();

    bf16x8 bfr[4][2];
    bf16x8 pa0, pa1, pa2, pa3;
    bf16x8 pb0, pb1, pb2, pb3;

#pragma unroll 1
    for (int it2 = 0; it2 < NI; ++it2) {
        int t = 2 * it2, t1 = t + 1;
        int ts2 = (t + 2 < NT) ? t + 2 : t;       // even -> buf0
        int ts3 = (t + 3 < NT) ? t + 3 : t1;      // odd  -> buf1
        // ---- tile t (buf0) ----
        RDB(0); RDAP(0,0); RDAQ(0,1); STA(1,t1,0);
            barrier_(); LGKM(4); MM(0, pa0,pa1,pa2,pa3); barrier_();
        RDAP(0,2); STA(1,t1,1);
            barrier_(); LGKM(4); MM(1, pb0,pb1,pb2,pb3); barrier_();
        RDAQ(0,3); STB(0,ts2,0);
            barrier_(); LGKM(4); MM(2, pa0,pa1,pa2,pa3); barrier_();
        STB(0,ts2,1); VMCNT(4);
            barrier_(); LGKM(0); MM(3, pb0,pb1,pb2,pb3); barrier_();
        // ---- tile t+1 (buf1) ----
        RDB(1); RDAP(1,0); RDAQ(1,1); STA(0,ts2,0);
            barrier_(); LGKM(4); MM(0, pa0,pa1,pa2,pa3); barrier_();
        RDAP(1,2); STA(0,ts2,1);
            barrier_(); LGKM(4); MM(1, pb0,pb1,pb2,pb3); barrier_();
        RDAQ(1,3); STB(1,ts3,0);
            barrier_(); LGKM(4); MM(2, pa0,pa1,pa2,pa3); barrier_();
        STB(1,ts3,1); VMCNT(4);
            barrier_(); LGKM(0); MM(3, pb0,pb1,pb2,pb3); barrier_();
    }
    VMCNT(0);   // drain in-flight LDS DMA before workgroup exit

    // epilogue
    long row0 = bm + wm * 128 + quad * 4;
    long col0 = bn + wn * 64 + l15;
#pragma unroll
    for (int i = 0; i < 8; ++i) {
        long row = row0 + i * 16;
#pragma unroll
        for (int j = 0; j < 4; ++j) {
            long col = col0 + j * 16;
            float bv = (BIAS && (!SPLITK || kz == 0)) ? bias[col] : 0.f;
#pragma unroll
            for (int r = 0; r < 4; ++r) {
                float v = acc[i][j][r] + bv;
                if (RES) v += res[(row + r) * ldc + col];
                if (RELU) v = fmaxf(v, 0.f);
                if (SPLITK) atomicAdd(&((float*)Cv)[(row + r) * ldc + col], v);
                else if (OUTF32) ((float*)Cv)[(row + r) * ldc + col] = v;
                else ((u16*)Cv)[(row + r) * ldc + col] = f2bf(v);
            }
        }
    }
}

template<int BIAS, int RES, int RELU, int OUTF32, int SPLITK>
__global__ __launch_bounds__(512) void gemm256(
    const u16* __restrict__ A, const u16* __restrict__ Bt,
    const float* __restrict__ bias, const float* __restrict__ res,
    void* __restrict__ Cv, int tilesM, int K, int ldc) {
    __shared__ u16 As[2 * 256 * 64];
    __shared__ u16 Bs[2 * 256 * 64];
    int id = blockIdx.x;
    long bm = (long)(id % tilesM) * 256, bn = (long)(id / tilesM) * 256;
    int kLen = SPLITK ? (K >> 1) : K;
    int koff = SPLITK ? ((int)blockIdx.y * kLen) : 0;
    gemm256_body<BIAS, RES, RELU, OUTF32, SPLITK>(
        A, Bt, bias, res, Cv, bm, bn, K, kLen, koff, ldc, blockIdx.y, As, Bs);
}

// Merged cross-attention projections, one 384-block dispatch:
//   id <  128: qbuf[8192,1024] = hq @ wT[0]^T
//   id >= 128: kv [8192,2048] = encb @ wT[1..2]^T
__global__ __launch_bounds__(512) void gemm256_cross(
    const u16* __restrict__ hq, const u16* __restrict__ encb,
    const u16* __restrict__ wT, u16* __restrict__ qbuf, u16* __restrict__ kv) {
    __shared__ u16 As[2 * 256 * 64];
    __shared__ u16 Bs[2 * 256 * 64];
    int id = blockIdx.x;
    const u16* A; const u16* Bt; u16* C; int ldc;
    if (id < 128) { A = hq; Bt = wT; C = qbuf; ldc = 1024; }
    else { id -= 128; A = encb; Bt = wT + 1024l * 1024l; C = kv; ldc = 2048; }
    long bm = (long)(id % 32) * 256, bn = (long)(id / 32) * 256;
    gemm256_body<0, 0, 0, 0, 0>(
        A, Bt, nullptr, nullptr, C, bm, bn, 1024, 1024, 0, ldc, 0, As, Bs);
}

// ---------------------------------------------------------------------------
// Flash attention (bf16). Grid (T/64, H, B); 4 waves x 16 Q rows.
// q/k row strides qld/kld (fused-QKV layouts); vT: [B][H][64][S]; out ld 1024.
// Wave-shared running max; deferred l reduction; exp2 w/ folded 1/8 scale.
// ---------------------------------------------------------------------------
template<bool CAUSAL>
__global__ __launch_bounds__(256) void attn_kernel(
    const u16* __restrict__ q, const u16* __restrict__ k,
    const u16* __restrict__ vT, u16* __restrict__ out, int qld, int kld) {
    __shared__ u16 Qs[64][72];
    __shared__ u16 Ks[64][72];
    __shared__ u16 VTs[64][72];
    __shared__ u16 Ps[4][16][72];
    const int S_ = 1024;
    int qt = CAUSAL ? (gridDim.x - 1 - blockIdx.x) : blockIdx.x;
    int h = blockIdx.y, b = blockIdx.z;
    int tid = threadIdx.x, lane = tid & 63, wv = tid >> 6;
    int l15 = lane & 15, quad = lane >> 4;
    long qbase = ((long)b * 1024 + qt * 64) * qld + h * 64;
    long obase = ((long)b * 1024 + qt * 64) * 1024 + h * 64;
#pragma unroll
    for (int it = 0; it < 2; ++it) {
        int f = it * 2048 + tid * 8;
        int r = f >> 6, c = f & 63;
        *(uint4*)&Qs[r][c] = *(const uint4*)&q[qbase + (long)r * qld + c];
    }
    __syncthreads();
    bf16x8 a0 = *(const bf16x8*)&Qs[wv * 16 + l15][quad * 8];
    bf16x8 a1 = *(const bf16x8*)&Qs[wv * 16 + l15][quad * 8 + 32];
    f32x4 zf = {0.f, 0.f, 0.f, 0.f};
    f32x4 O[4];
#pragma unroll
    for (int j = 0; j < 4; ++j) O[j] = zf;
    const float cs = 0.125f * 1.44269504089f;   // fold 1/sqrt(64) into exp2
    float m_run = -3e30f;                       // wave-shared (16 rows)
    float lp[4] = {0.f, 0.f, 0.f, 0.f};        // per-lane partial l
    long kbase = (long)b * 1024 * kld + h * 64;
    long vtbase = ((long)b * 16 + h) * 64 * (long)S_;
    int ktmax = CAUSAL ? qt : (S_ / 64 - 1);

    for (int kt = 0; kt <= ktmax; ++kt) {
        __syncthreads();
#pragma unroll
        for (int it = 0; it < 2; ++it) {
            int f = it * 2048 + tid * 8;
            int r = f >> 6, c = f & 63;
            *(uint4*)&Ks[r][c]  = *(const uint4*)&k[kbase + (long)(kt * 64 + r) * kld + c];
            *(uint4*)&VTs[r][c] = *(const uint4*)&vT[vtbase + (long)r * S_ + kt * 64 + c];
        }
        __syncthreads();

        f32x4 s[4];
#pragma unroll
        for (int j = 0; j < 4; ++j) {
            bf16x8 kb0 = *(const bf16x8*)&Ks[j * 16 + l15][quad * 8];
            bf16x8 kb1 = *(const bf16x8*)&Ks[j * 16 + l15][quad * 8 + 32];
            f32x4 z = zf;
            z = __builtin_amdgcn_mfma_f32_16x16x32_bf16(a0, kb0, z, 0, 0, 0);
            z = __builtin_amdgcn_mfma_f32_16x16x32_bf16(a1, kb1, z, 0, 0, 0);
            s[j] = z;
        }
        if (CAUSAL && kt == qt) {
#pragma unroll
            for (int j = 0; j < 4; ++j)
#pragma unroll
                for (int r = 0; r < 4; ++r)
                    if ((j * 16 + l15) > (wv * 16 + quad * 4 + r)) s[j][r] = -3e30f;
        }
        float mx = s[0][0];
#pragma unroll
        for (int j = 0; j < 4; ++j)
#pragma unroll
            for (int r = 0; r < 4; ++r) mx = fmaxf(mx, s[j][r]);
#pragma unroll
        for (int o = 1; o < 64; o <<= 1) mx = fmaxf(mx, __shfl_xor(mx, o, 64));
        float mn = fmaxf(m_run, mx);
        bool grew = mn > m_run;
        if (grew) {
            float alpha = fexp2((m_run - mn) * cs);
            m_run = mn;
#pragma unroll
            for (int j = 0; j < 4; ++j) {
                O[j][0] *= alpha; O[j][1] *= alpha; O[j][2] *= alpha; O[j][3] *= alpha;
            }
#pragma unroll
            for (int r = 0; r < 4; ++r) lp[r] *= alpha;
        }
        float mc = m_run * cs;
#pragma unroll
        for (int j = 0; j < 4; ++j)
#pragma unroll
            for (int r = 0; r < 4; ++r) {
                float p = fexp2(__builtin_fmaf(s[j][r], cs, -mc));
                lp[r] += p;
                Ps[wv][quad * 4 + r][j * 16 + l15] = f2bf_fast(p);
            }
        bf16x8 pa0 = *(const bf16x8*)&Ps[wv][l15][quad * 8];
        bf16x8 pa1 = *(const bf16x8*)&Ps[wv][l15][quad * 8 + 32];
#pragma unroll
        for (int j = 0; j < 4; ++j) {
            bf16x8 vb0 = *(const bf16x8*)&VTs[j * 16 + l15][quad * 8];
            bf16x8 vb1 = *(const bf16x8*)&VTs[j * 16 + l15][quad * 8 + 32];
            f32x4 o = O[j];
            o = __builtin_amdgcn_mfma_f32_16x16x32_bf16(pa0, vb0, o, 0, 0, 0);
            o = __builtin_amdgcn_mfma_f32_16x16x32_bf16(pa1, vb1, o, 0, 0, 0);
            O[j] = o;
        }
    }
#pragma unroll
    for (int r = 0; r < 4; ++r) {
#pragma unroll
        for (int o = 1; o < 16; o <<= 1) lp[r] += __shfl_xor(lp[r], o, 64);
        lp[r] = 1.f / lp[r];
    }
#pragma unroll
    for (int j = 0; j < 4; ++j)
#pragma unroll
        for (int r = 0; r < 4; ++r)
            out[obase + (long)(wv * 16 + quad * 4 + r) * 1024 + j * 16 + l15] =
                f2bf(O[j][r] * lp[r]);
}

// ---------------------------------------------------------------------------
// Workspace (u16 units; MEG = 1M; total 60 MEG = 120 MB):
//   0- 8 hbuf | 8-32 qkv (self) / cross: qbuf(8-16)+kv(16-32)
//  32-40 vTb / encb (encb dies before vTb written)
//  40-43 wT (q|k|v transposed, contiguous) | 43-44 wT3 (o)
//  44-60 x1 (f32); FFN: w1T 44-48, w2T 48-52 (x1 dead), ff1 8-40
//  x2 lives in d_out; FFN2 is split-K=2 with atomicAdd into out (out holds
//  x2 -> residual implicit; b2 added by z==0).
// ---------------------------------------------------------------------------
extern "C" void kernel_launch(void* const* d_in, const int* in_sizes, int n_in,
                              void* d_out, int out_size, void* d_ws, size_t ws_size,
                              hipStream_t stream) {
    (void)in_sizes; (void)n_in; (void)out_size; (void)ws_size;
    const float* x    = (const float*)d_in[0];
    const float* enc  = (const float*)d_in[1];
    // d_in[2]=tgt_mask, d_in[3]=src_mask: all-true; causal applied explicitly
    const float* ln1g = (const float*)d_in[4];
    const float* ln1b = (const float*)d_in[5];
    const float* ln2g = (const float*)d_in[6];
    const float* ln2b = (const float*)d_in[7];
    const float* ln3g = (const float*)d_in[8];
    const float* ln3b = (const float*)d_in[9];
    const float* Wq_s = (const float*)d_in[10];
    const float* Wk_s = (const float*)d_in[11];
    const float* Wv_s = (const float*)d_in[12];
    const float* Wo_s = (const float*)d_in[13];
    const float* bo_s = (const float*)d_in[14];
    const float* Wq_c = (const float*)d_in[15];
    const float* Wk_c = (const float*)d_in[16];
    const float* Wv_c = (const float*)d_in[17];
    const float* Wo_c = (const float*)d_in[18];
    const float* bo_c = (const float*)d_in[19];
    const float* W1   = (const float*)d_in[20];
    const float* b1   = (const float*)d_in[21];
    const float* W2   = (const float*)d_in[22];
    const float* b2   = (const float*)d_in[23];
    float* out = (float*)d_out;

    const long MEG = 1024l * 1024l;
    u16* ws0  = (u16*)d_ws;
    u16* hbuf = ws0 + 0 * MEG;
    u16* qkv  = ws0 + 8 * MEG;            // self: [8192][3072]
    u16* qbuf = ws0 + 8 * MEG;            // cross: [8192][1024]
    u16* kv   = ws0 + 16 * MEG;           // cross: [8192][2048]
    u16* vTb  = ws0 + 32 * MEG;
    u16* encb = ws0 + 32 * MEG;           // dead before vTb is written
    u16* wT   = ws0 + 40 * MEG;           // 3 contiguous MEG: q|k|v transposed
    u16* wT3  = ws0 + 43 * MEG;
    float* x1 = (float*)(ws0 + 44 * MEG); // 8M f32
    u16* ff1  = qkv;                      // 8-40 MEG after attention buffers die
    u16* w1T  = ws0 + 44 * MEG;           // after x1 dies
    u16* w2T  = ws0 + 48 * MEG;

    dim3 blk(256);
    dim3 blk5(512);
    dim3 gW4(16, 16, 4);      // batched 4x 1024^2 weight transpose
    dim3 gA(16, 16, 8);       // attention / batched v-transpose

    // ---- self attention ----
    transpose_w4<<<gW4, blk, 0, stream>>>(Wq_s, Wk_s, Wv_s, Wo_s, wT);  // wT3=wT+3M
    ln_kernel<<<8192, blk, 0, stream>>>(x, ln1g, ln1b, hbuf);
    gemm256<0,0,0,0,0><<<384, blk5, 0, stream>>>(hbuf, wT, nullptr, nullptr, qkv, 32, 1024, 3072);
    transpose_b<<<gA, blk, 0, stream>>>(qkv + 2048, vTb, 1024, 1024, 3072, 1024l * 3072, MEG);
    attn_kernel<true><<<gA, blk, 0, stream>>>(qkv, qkv + 1024, vTb, hbuf, 3072, 3072);
    gemm256<1,1,0,1,0><<<128, blk5, 0, stream>>>(hbuf, wT3, bo_s, x, x1, 32, 1024, 1024);

    // ---- cross attention ----
    transpose_w4<<<gW4, blk, 0, stream>>>(Wq_c, Wk_c, Wv_c, Wo_c, wT);
    ln_kernel<<<8192, blk, 0, stream>>>(x1, ln2g, ln2b, hbuf);
    convert_f32_bf16<<<8192, blk, 0, stream>>>(enc, encb);
    gemm256_cross<<<384, blk5, 0, stream>>>(hbuf, encb, wT, qbuf, kv);
    transpose_b<<<gA, blk, 0, stream>>>(kv + 1024, vTb, 1024, 1024, 2048, 1024l * 2048, MEG);  // encb dead
    attn_kernel<false><<<gA, blk, 0, stream>>>(qbuf, kv, vTb, hbuf, 1024, 2048);
    gemm256<1,1,0,1,0><<<128, blk5, 0, stream>>>(hbuf, wT3, bo_c, x1, out, 32, 1024, 1024);

    // ---- FFN (x1 dead; w1T/w2T reuse its slot) ----
    transpose_w<<<dim3(64, 16, 1), blk, 0, stream>>>(W1, w1T, 1024, 4096);
    transpose_w<<<dim3(16, 64, 1), blk, 0, stream>>>(W2, w2T, 4096, 1024);
    ln_kernel<<<8192, blk, 0, stream>>>(out, ln3g, ln3b, hbuf);
    gemm256<1,0,1,0,0><<<512, blk5, 0, stream>>>(hbuf, w1T, b1, nullptr, ff1, 32, 1024, 4096);
    // split-K=2: out already holds x2 (residual); z=0 adds b2.
    gemm256<1,0,0,1,1><<<dim3(128, 2), blk5, 0, stream>>>(ff1, w2T, b2, nullptr, out, 32, 4096, 1024);
}

// Round 4
// 751.174 us; speedup vs baseline: 1.0920x; 1.0076x over previous
//
#include <hip/hip_runtime.h>

typedef unsigned short u16;
typedef __attribute__((ext_vector_type(8))) short bf16x8;   // 8 bf16 = 4 VGPRs
typedef __attribute__((ext_vector_type(4))) float f32x4;

__device__ __forceinline__ float bf2f(u16 u) {
    return __uint_as_float(((unsigned)u) << 16);
}
__device__ __forceinline__ u16 f2bf(float f) {          // RNE (outputs)
    unsigned u = __float_as_uint(f);
    u = (u + 0x7fffu + ((u >> 16) & 1u)) >> 16;
    return (u16)u;
}
__device__ __forceinline__ u16 f2bf_fast(float f) {     // RN w/o tie fix (P only)
    return (u16)((__float_as_uint(f) + 0x8000u) >> 16);
}
__device__ __forceinline__ float fexp2(float x) { return __builtin_amdgcn_exp2f(x); }
__device__ __forceinline__ void gld_lds16(const u16* g, u16* l) {
    __builtin_amdgcn_global_load_lds(
        (const __attribute__((address_space(1))) void*)g,
        (__attribute__((address_space(3))) void*)l, 16, 0, 0);
}
__device__ __forceinline__ unsigned lds_off(const u16* p) {
    return (unsigned)(unsigned long long)(const __attribute__((address_space(3))) u16*)p;
}
__device__ __forceinline__ void barrier_() {
    asm volatile("" ::: "memory");
    __builtin_amdgcn_s_barrier();
    asm volatile("" ::: "memory");
}
#define VMCNT(n) asm volatile("s_waitcnt vmcnt(" #n ")" ::: "memory")
// rule 18: lgkmcnt via asm MUST be followed by sched_barrier(0) so register-only
// MFMAs can't be hoisted above the wait.
#define LGKM(n) do { \
    asm volatile("s_waitcnt lgkmcnt(" #n ")" ::: "memory"); \
    __builtin_amdgcn_sched_barrier(0); \
} while(0)
#define DSR(dst, addr) asm volatile("ds_read_b128 %0, %1" : "=v"(dst) : "v"(addr))

// ---------------------------------------------------------------------------
// convert: f32 -> bf16, 4 elems/thread.
// ---------------------------------------------------------------------------
__global__ __launch_bounds__(256) void convert_f32_bf16(
    const float* __restrict__ in, u16* __restrict__ out) {
    long i = ((long)blockIdx.x * 256 + threadIdx.x) * 4;
    float4 v = *(const float4*)&in[i];
    alignas(8) u16 o[4] = {f2bf(v.x), f2bf(v.y), f2bf(v.z), f2bf(v.w)};
    *(uint2*)&out[i] = *(const uint2*)o;
}

// ---------------------------------------------------------------------------
// Weight transpose + downcast: f32 [R][C] -> bf16 [C][R], 64x64 tiles.
// ---------------------------------------------------------------------------
__device__ __forceinline__ void transpose_w_body(
    const float* __restrict__ in, u16* __restrict__ out, int R, int C) {
    __shared__ u16 tile[64][72];
    int r0 = blockIdx.y * 64, c0 = blockIdx.x * 64;
    int tid = threadIdx.x;
#pragma unroll
    for (int it = 0; it < 4; ++it) {
        int f = it * 1024 + tid * 4;
        int r = f >> 6, c = f & 63;
        float4 v = *(const float4*)&in[(long)(r0 + r) * C + (c0 + c)];
        alignas(8) u16 o[4] = {f2bf(v.x), f2bf(v.y), f2bf(v.z), f2bf(v.w)};
        *(uint2*)&tile[r][c] = *(const uint2*)o;
    }
    __syncthreads();
#pragma unroll
    for (int it = 0; it < 2; ++it) {
        int f = it * 2048 + tid * 8;
        int rr = f >> 6, cc = f & 63;
        alignas(16) u16 tmp[8];
#pragma unroll
        for (int i = 0; i < 8; ++i) tmp[i] = tile[cc + i][rr];
        *(uint4*)&out[(long)(c0 + rr) * R + (r0 + cc)] = *(const uint4*)tmp;
    }
}

__global__ __launch_bounds__(256) void transpose_w(
    const float* __restrict__ in, u16* __restrict__ out, int R, int C) {
    transpose_w_body(in, out, R, C);
}

// 4 batched 1024x1024 transposes (QKVO weights), z selects matrix.
__global__ __launch_bounds__(256) void transpose_w4(
    const float* __restrict__ p0, const float* __restrict__ p1,
    const float* __restrict__ p2, const float* __restrict__ p3,
    u16* __restrict__ out) {
    int z = blockIdx.z;
    const float* in = (z == 0) ? p0 : (z == 1) ? p1 : (z == 2) ? p2 : p3;
    transpose_w_body(in, out + (long)z * 1024 * 1024, 1024, 1024);
}

// ---------------------------------------------------------------------------
// bf16 transpose (for V), input row-stride istride, batched via blockIdx.z.
// ---------------------------------------------------------------------------
__global__ __launch_bounds__(256) void transpose_b(
    const u16* __restrict__ in, u16* __restrict__ out,
    int R, int C, int istride, long ibs, long obs) {
    __shared__ u16 tile[64][72];
    const u16* src = in + (long)blockIdx.z * ibs;
    u16* dst = out + (long)blockIdx.z * obs;
    int r0 = blockIdx.y * 64, c0 = blockIdx.x * 64;
    int tid = threadIdx.x;
#pragma unroll
    for (int it = 0; it < 2; ++it) {
        int f = it * 2048 + tid * 8;
        int r = f >> 6, c = f & 63;
        *(uint4*)&tile[r][c] = *(const uint4*)&src[(long)(r0 + r) * istride + (c0 + c)];
    }
    __syncthreads();
#pragma unroll
    for (int it = 0; it < 2; ++it) {
        int f = it * 2048 + tid * 8;
        int rr = f >> 6, cc = f & 63;
        alignas(16) u16 tmp[8];
#pragma unroll
        for (int i = 0; i < 8; ++i) tmp[i] = tile[cc + i][rr];
        *(uint4*)&dst[(long)(c0 + rr) * R + (r0 + cc)] = *(const uint4*)tmp;
    }
}

// ---------------------------------------------------------------------------
// LayerNorm rows of 1024: f32 in, f32 gamma/beta, bf16 out. One block/row.
// ---------------------------------------------------------------------------
__global__ __launch_bounds__(256) void ln_kernel(
    const float* __restrict__ x, const float* __restrict__ g,
    const float* __restrict__ bta, u16* __restrict__ y) {
    long row = blockIdx.x;
    int tid = threadIdx.x;
    float4 v4 = *(const float4*)&x[row * 1024 + tid * 4];
    float v[4] = {v4.x, v4.y, v4.z, v4.w};
    float s = 0.f, ss = 0.f;
#pragma unroll
    for (int i = 0; i < 4; ++i) { s += v[i]; ss += v[i] * v[i]; }
#pragma unroll
    for (int o = 1; o < 64; o <<= 1) { s += __shfl_xor(s, o, 64); ss += __shfl_xor(ss, o, 64); }
    __shared__ float red[8];
    int wv = tid >> 6, lane = tid & 63;
    if (lane == 0) { red[wv] = s; red[4 + wv] = ss; }
    __syncthreads();
    s = red[0] + red[1] + red[2] + red[3];
    ss = red[4] + red[5] + red[6] + red[7];
    float mean = s * (1.f / 1024.f);
    float var = ss * (1.f / 1024.f) - mean * mean;
    float rs = rsqrtf(var + 1e-5f);
    float4 g4 = *(const float4*)&g[tid * 4];
    float4 b4 = *(const float4*)&bta[tid * 4];
    float gg[4] = {g4.x, g4.y, g4.z, g4.w};
    float bb[4] = {b4.x, b4.y, b4.z, b4.w};
    alignas(8) u16 o4[4];
#pragma unroll
    for (int i = 0; i < 4; ++i)
        o4[i] = f2bf((v[i] - mean) * rs * gg[i] + bb[i]);
    *(uint2*)&y[row * 1024 + tid * 4] = *(const uint2*)o4;
}

// ---------------------------------------------------------------------------
// 256x256 8-phase GEMM (T2+T3+T4+T5). Deep stage ring:
//   p1: t+1.A (full, 4 loads)   p2: t+2.B0   p3: t+2.B1   p4: vmcnt(4)
//   p5: t+2.A (full, 4 loads)   p6: t+3.B0   p7: t+3.B1   p8: vmcnt(4)
// Hazards (verified): every p4/p8 vmcnt(4) completes exactly the tiles the
// next 4 phases read (t+1.{A,B} at p4; t+2.{A,B} at p8) and leaves 4 loads
// (next B-tile) in flight. Min issue->consume distance = 4 phases.
// Reads are per-phase (RDB+RDA) with lgkmcnt(0) after the barrier (R2-best).
// XCD super-tile map (tilesM==32 always): XCD c=id%8 owns bm-tiles 4c..4c+3
// (A 2MB pinned in its L2); walks bn in 4-tile groups (B 2MB/super-tile)
// -> 4MB/XCD footprint, stage misses only at super-tile edges. Bijective for
// tilesN in {4,8,12,16}.
// LDS swizzle slot^=(row&7): inverse-swizzled global src + swizzled read.
// ---------------------------------------------------------------------------
#define STA(b,t,h) do { \
    gld_lds16(Ag + ((h)*128 +  0) * (long)K + (t)*64, AsL + (b)*16384 + (h)*8192); \
    gld_lds16(Ag + ((h)*128 + 64) * (long)K + (t)*64, AsL + (b)*16384 + (h)*8192 + 4096); \
} while(0)
#define STB(b,t,h) do { \
    gld_lds16(Bg + ((h)*128 +  0) * (long)K + (t)*64, BsL + (b)*16384 + (h)*8192); \
    gld_lds16(Bg + ((h)*128 + 64) * (long)K + (t)*64, BsL + (b)*16384 + (h)*8192 + 4096); \
} while(0)
#define RDB(b) do { \
    DSR(bfr[0][0], aB0 + (b)*32768 +    0); DSR(bfr[0][1], aB1 + (b)*32768 +    0); \
    DSR(bfr[1][0], aB0 + (b)*32768 + 2048); DSR(bfr[1][1], aB1 + (b)*32768 + 2048); \
    DSR(bfr[2][0], aB0 + (b)*32768 + 4096); DSR(bfr[2][1], aB1 + (b)*32768 + 4096); \
    DSR(bfr[3][0], aB0 + (b)*32768 + 6144); DSR(bfr[3][1], aB1 + (b)*32768 + 6144); \
} while(0)
#define RDA(b,q) do { \
    DSR(a0, aA0 + (b)*32768 + (2*(q)  )*2048); \
    DSR(a1, aA1 + (b)*32768 + (2*(q)  )*2048); \
    DSR(a2, aA0 + (b)*32768 + (2*(q)+1)*2048); \
    DSR(a3, aA1 + (b)*32768 + (2*(q)+1)*2048); \
} while(0)
#define MM(q) do { \
    __builtin_amdgcn_s_setprio(1); \
    _Pragma("unroll") \
    for (int j = 0; j < 4; ++j) { \
        acc[2*(q)  ][j] = __builtin_amdgcn_mfma_f32_16x16x32_bf16(a0, bfr[j][0], acc[2*(q)  ][j], 0, 0, 0); \
        acc[2*(q)  ][j] = __builtin_amdgcn_mfma_f32_16x16x32_bf16(a1, bfr[j][1], acc[2*(q)  ][j], 0, 0, 0); \
        acc[2*(q)+1][j] = __builtin_amdgcn_mfma_f32_16x16x32_bf16(a2, bfr[j][0], acc[2*(q)+1][j], 0, 0, 0); \
        acc[2*(q)+1][j] = __builtin_amdgcn_mfma_f32_16x16x32_bf16(a3, bfr[j][1], acc[2*(q)+1][j], 0, 0, 0); } \
    __builtin_amdgcn_s_setprio(0); \
} while(0)

// XCD-pinned 4x4 super-tile block mapping (tilesM must be 32).
__device__ __forceinline__ void supertile_map(int id, long& bm, long& bn) {
    int c = id & 7, j = id >> 3;
    int k = j >> 4, off = j & 15;
    bm = (long)(c * 4 + (off & 3)) * 256;
    bn = (long)(k * 4 + (off >> 2)) * 256;
}

template<int BIAS, int RES, int RELU, int OUTF32, int SPLITK>
__device__ __forceinline__ void gemm256_body(
    const u16* __restrict__ A, const u16* __restrict__ Bt,
    const float* __restrict__ bias, const float* __restrict__ res,
    void* __restrict__ Cv, long bm, long bn, int K, int kLen, int koff,
    int ldc, int kz, u16* As, u16* Bs) {
    int tid = threadIdx.x;
    int lane = tid & 63;
    int l15 = lane & 15, quad = lane >> 4;
    int wv = tid >> 6, wm = wv >> 2, wn = wv & 3;
    int NT = kLen >> 6, NI = NT >> 1;

    // staging addresses (linear LDS dest, inverse-swizzled global source)
    int srow = tid >> 3;                                // 0..63
    int scol = ((tid & 7) ^ (srow & 7)) << 3;           // u16 elems
    const u16* Ag = A + (bm + srow) * (long)K + koff + scol;
    const u16* Bg = Bt + (bn + srow) * (long)K + koff + scol;
    u16* AsL = As + tid * 8;
    u16* BsL = Bs + tid * 8;

    // fragment read addresses (swizzled), as 32-bit LDS byte addresses
    int c0 = (quad * 8) ^ ((l15 & 7) << 3);
    int c1 = (32 + quad * 8) ^ ((l15 & 7) << 3);
    unsigned arB = lds_off(As + (wm * 128 + l15) * 64);
    unsigned brB = lds_off(Bs + (wn * 64 + l15) * 64);
    unsigned aA0 = arB + 2 * c0, aA1 = arB + 2 * c1;
    unsigned aB0 = brB + 2 * c0, aB1 = brB + 2 * c1;

    f32x4 zf = {0.f, 0.f, 0.f, 0.f};
    f32x4 acc[8][4];
#pragma unroll
    for (int i = 0; i < 8; ++i)
#pragma unroll
        for (int j = 0; j < 4; ++j) acc[i][j] = zf;

    // prologue: t0.{A,B} (8 loads) + t1.B (4); vmcnt(4) lands t0, t1.B flies.
    STA(0,0,0); STA(0,0,1); STB(0,0,0); STB(0,0,1); STB(1,1,0); STB(1,1,1);
    VMCNT(4);
    barrier_();

    bf16x8 bfr[4][2];
    bf16x8 a0, a1, a2, a3;

#pragma unroll 1
    for (int it2 = 0; it2 < NI; ++it2) {
        int t = 2 * it2, t1 = t + 1;
        int ts2 = (t + 2 < NT) ? t + 2 : t;       // even -> buf0
        int ts3 = (t + 3 < NT) ? t + 3 : t1;      // odd  -> buf1
        // ---- tile t (buf0) ----
        RDB(0); RDA(0,0); STA(1,t1,0); STA(1,t1,1);
            barrier_(); LGKM(0); MM(0); barrier_();
        RDA(0,1); STB(0,ts2,0);
            barrier_(); LGKM(0); MM(1); barrier_();
        RDA(0,2); STB(0,ts2,1);
            barrier_(); LGKM(0); MM(2); barrier_();
        RDA(0,3); VMCNT(4);
            barrier_(); LGKM(0); MM(3); barrier_();
        // ---- tile t+1 (buf1) ----
        RDB(1); RDA(1,0); STA(0,ts2,0); STA(0,ts2,1);
            barrier_(); LGKM(0); MM(0); barrier_();
        RDA(1,1); STB(1,ts3,0);
            barrier_(); LGKM(0); MM(1); barrier_();
        RDA(1,2); STB(1,ts3,1);
            barrier_(); LGKM(0); MM(2); barrier_();
        RDA(1,3); VMCNT(4);
            barrier_(); LGKM(0); MM(3); barrier_();
    }
    VMCNT(0);   // drain in-flight LDS DMA before workgroup exit

    // epilogue
    long row0 = bm + wm * 128 + quad * 4;
    long col0 = bn + wn * 64 + l15;
#pragma unroll
    for (int i = 0; i < 8; ++i) {
        long row = row0 + i * 16;
#pragma unroll
        for (int j = 0; j < 4; ++j) {
            long col = col0 + j * 16;
            float bv = (BIAS && (!SPLITK || kz == 0)) ? bias[col] : 0.f;
#pragma unroll
            for (int r = 0; r < 4; ++r) {
                float v = acc[i][j][r] + bv;
                if (RES) v += res[(row + r) * ldc + col];
                if (RELU) v = fmaxf(v, 0.f);
                if (SPLITK) atomicAdd(&((float*)Cv)[(row + r) * ldc + col], v);
                else if (OUTF32) ((float*)Cv)[(row + r) * ldc + col] = v;
                else ((u16*)Cv)[(row + r) * ldc + col] = f2bf(v);
            }
        }
    }
}

template<int BIAS, int RES, int RELU, int OUTF32, int SPLITK>
__global__ __launch_bounds__(512) void gemm256(
    const u16* __restrict__ A, const u16* __restrict__ Bt,
    const float* __restrict__ bias, const float* __restrict__ res,
    void* __restrict__ Cv, int tilesM, int K, int ldc) {
    __shared__ u16 As[2 * 256 * 64];
    __shared__ u16 Bs[2 * 256 * 64];
    (void)tilesM;
    long bm, bn;
    supertile_map(blockIdx.x, bm, bn);
    int kLen = SPLITK ? (K >> 1) : K;
    int koff = SPLITK ? ((int)blockIdx.y * kLen) : 0;
    gemm256_body<BIAS, RES, RELU, OUTF32, SPLITK>(
        A, Bt, bias, res, Cv, bm, bn, K, kLen, koff, ldc, blockIdx.y, As, Bs);
}

// Merged cross-attention projections, one 384-block dispatch:
//   id <  128: qbuf[8192,1024] = hq @ wT[0]^T
//   id >= 128: kv [8192,2048] = encb @ wT[1..2]^T
// (128 % 8 == 0, so local-id XCD affinity == global-id affinity.)
__global__ __launch_bounds__(512) void gemm256_cross(
    const u16* __restrict__ hq, const u16* __restrict__ encb,
    const u16* __restrict__ wT, u16* __restrict__ qbuf, u16* __restrict__ kv) {
    __shared__ u16 As[2 * 256 * 64];
    __shared__ u16 Bs[2 * 256 * 64];
    int id = blockIdx.x;
    const u16* A; const u16* Bt; u16* C; int ldc;
    if (id < 128) { A = hq; Bt = wT; C = qbuf; ldc = 1024; }
    else { id -= 128; A = encb; Bt = wT + 1024l * 1024l; C = kv; ldc = 2048; }
    long bm, bn;
    supertile_map(id, bm, bn);
    gemm256_body<0, 0, 0, 0, 0>(
        A, Bt, nullptr, nullptr, C, bm, bn, 1024, 1024, 0, ldc, 0, As, Bs);
}

// ---------------------------------------------------------------------------
// Flash attention (bf16). Grid (T/64, H, B); 4 waves x 16 Q rows.
// q/k row strides qld/kld (fused-QKV layouts); vT: [B][H][64][S]; out ld 1024.
// Wave-shared running max; deferred l reduction; exp2 w/ folded 1/8 scale.
// ---------------------------------------------------------------------------
template<bool CAUSAL>
__global__ __launch_bounds__(256) void attn_kernel(
    const u16* __restrict__ q, const u16* __restrict__ k,
    const u16* __restrict__ vT, u16* __restrict__ out, int qld, int kld) {
    __shared__ u16 Qs[64][72];
    __shared__ u16 Ks[64][72];
    __shared__ u16 VTs[64][72];
    __shared__ u16 Ps[4][16][72];
    const int S_ = 1024;
    int qt = CAUSAL ? (gridDim.x - 1 - blockIdx.x) : blockIdx.x;
    int h = blockIdx.y, b = blockIdx.z;
    int tid = threadIdx.x, lane = tid & 63, wv = tid >> 6;
    int l15 = lane & 15, quad = lane >> 4;
    long qbase = ((long)b * 1024 + qt * 64) * qld + h * 64;
    long obase = ((long)b * 1024 + qt * 64) * 1024 + h * 64;
#pragma unroll
    for (int it = 0; it < 2; ++it) {
        int f = it * 2048 + tid * 8;
        int r = f >> 6, c = f & 63;
        *(uint4*)&Qs[r][c] = *(const uint4*)&q[qbase + (long)r * qld + c];
    }
    __syncthreads();
    bf16x8 a0 = *(const bf16x8*)&Qs[wv * 16 + l15][quad * 8];
    bf16x8 a1 = *(const bf16x8*)&Qs[wv * 16 + l15][quad * 8 + 32];
    f32x4 zf = {0.f, 0.f, 0.f, 0.f};
    f32x4 O[4];
#pragma unroll
    for (int j = 0; j < 4; ++j) O[j] = zf;
    const float cs = 0.125f * 1.44269504089f;   // fold 1/sqrt(64) into exp2
    float m_run = -3e30f;                       // wave-shared (16 rows)
    float lp[4] = {0.f, 0.f, 0.f, 0.f};        // per-lane partial l
    long kbase = (long)b * 1024 * kld + h * 64;
    long vtbase = ((long)b * 16 + h) * 64 * (long)S_;
    int ktmax = CAUSAL ? qt : (S_ / 64 - 1);

    for (int kt = 0; kt <= ktmax; ++kt) {
        __syncthreads();
#pragma unroll
        for (int it = 0; it < 2; ++it) {
            int f = it * 2048 + tid * 8;
            int r = f >> 6, c = f & 63;
            *(uint4*)&Ks[r][c]  = *(const uint4*)&k[kbase + (long)(kt * 64 + r) * kld + c];
            *(uint4*)&VTs[r][c] = *(const uint4*)&vT[vtbase + (long)r * S_ + kt * 64 + c];
        }
        __syncthreads();

        f32x4 s[4];
#pragma unroll
        for (int j = 0; j < 4; ++j) {
            bf16x8 kb0 = *(const bf16x8*)&Ks[j * 16 + l15][quad * 8];
            bf16x8 kb1 = *(const bf16x8*)&Ks[j * 16 + l15][quad * 8 + 32];
            f32x4 z = zf;
            z = __builtin_amdgcn_mfma_f32_16x16x32_bf16(a0, kb0, z, 0, 0, 0);
            z = __builtin_amdgcn_mfma_f32_16x16x32_bf16(a1, kb1, z, 0, 0, 0);
            s[j] = z;
        }
        if (CAUSAL && kt == qt) {
#pragma unroll
            for (int j = 0; j < 4; ++j)
#pragma unroll
                for (int r = 0; r < 4; ++r)
                    if ((j * 16 + l15) > (wv * 16 + quad * 4 + r)) s[j][r] = -3e30f;
        }
        float mx = s[0][0];
#pragma unroll
        for (int j = 0; j < 4; ++j)
#pragma unroll
            for (int r = 0; r < 4; ++r) mx = fmaxf(mx, s[j][r]);
#pragma unroll
        for (int o = 1; o < 64; o <<= 1) mx = fmaxf(mx, __shfl_xor(mx, o, 64));
        float mn = fmaxf(m_run, mx);
        bool grew = mn > m_run;
        if (grew) {
            float alpha = fexp2((m_run - mn) * cs);
            m_run = mn;
#pragma unroll
            for (int j = 0; j < 4; ++j) {
                O[j][0] *= alpha; O[j][1] *= alpha; O[j][2] *= alpha; O[j][3] *= alpha;
            }
#pragma unroll
            for (int r = 0; r < 4; ++r) lp[r] *= alpha;
        }
        float mc = m_run * cs;
#pragma unroll
        for (int j = 0; j < 4; ++j)
#pragma unroll
            for (int r = 0; r < 4; ++r) {
                float p = fexp2(__builtin_fmaf(s[j][r], cs, -mc));
                lp[r] += p;
                Ps[wv][quad * 4 + r][j * 16 + l15] = f2bf_fast(p);
            }
        bf16x8 pa0 = *(const bf16x8*)&Ps[wv][l15][quad * 8];
        bf16x8 pa1 = *(const bf16x8*)&Ps[wv][l15][quad * 8 + 32];
#pragma unroll
        for (int j = 0; j < 4; ++j) {
            bf16x8 vb0 = *(const bf16x8*)&VTs[j * 16 + l15][quad * 8];
            bf16x8 vb1 = *(const bf16x8*)&VTs[j * 16 + l15][quad * 8 + 32];
            f32x4 o = O[j];
            o = __builtin_amdgcn_mfma_f32_16x16x32_bf16(pa0, vb0, o, 0, 0, 0);
            o = __builtin_amdgcn_mfma_f32_16x16x32_bf16(pa1, vb1, o, 0, 0, 0);
            O[j] = o;
        }
    }
#pragma unroll
    for (int r = 0; r < 4; ++r) {
#pragma unroll
        for (int o = 1; o < 16; o <<= 1) lp[r] += __shfl_xor(lp[r], o, 64);
        lp[r] = 1.f / lp[r];
    }
#pragma unroll
    for (int j = 0; j < 4; ++j)
#pragma unroll
        for (int r = 0; r < 4; ++r)
            out[obase + (long)(wv * 16 + quad * 4 + r) * 1024 + j * 16 + l15] =
                f2bf(O[j][r] * lp[r]);
}

// ---------------------------------------------------------------------------
// Workspace (u16 units; MEG = 1M; total 60 MEG = 120 MB):
//   0- 8 hbuf | 8-32 qkv (self) / cross: qbuf(8-16)+kv(16-32)
//  32-40 vTb / encb (encb dies before vTb written)
//  40-43 wT (q|k|v transposed, contiguous) | 43-44 wT3 (o)
//  44-60 x1 (f32); FFN: w1T 44-48, w2T 48-52 (x1 dead), ff1 8-40
//  x2 lives in d_out; FFN2 is split-K=2 with atomicAdd into out (out holds
//  x2 -> residual implicit; b2 added by z==0).
// ---------------------------------------------------------------------------
extern "C" void kernel_launch(void* const* d_in, const int* in_sizes, int n_in,
                              void* d_out, int out_size, void* d_ws, size_t ws_size,
                              hipStream_t stream) {
    (void)in_sizes; (void)n_in; (void)out_size; (void)ws_size;
    const float* x    = (const float*)d_in[0];
    const float* enc  = (const float*)d_in[1];
    // d_in[2]=tgt_mask, d_in[3]=src_mask: all-true; causal applied explicitly
    const float* ln1g = (const float*)d_in[4];
    const float* ln1b = (const float*)d_in[5];
    const float* ln2g = (const float*)d_in[6];
    const float* ln2b = (const float*)d_in[7];
    const float* ln3g = (const float*)d_in[8];
    const float* ln3b = (const float*)d_in[9];
    const float* Wq_s = (const float*)d_in[10];
    const float* Wk_s = (const float*)d_in[11];
    const float* Wv_s = (const float*)d_in[12];
    const float* Wo_s = (const float*)d_in[13];
    const float* bo_s = (const float*)d_in[14];
    const float* Wq_c = (const float*)d_in[15];
    const float* Wk_c = (const float*)d_in[16];
    const float* Wv_c = (const float*)d_in[17];
    const float* Wo_c = (const float*)d_in[18];
    const float* bo_c = (const float*)d_in[19];
    const float* W1   = (const float*)d_in[20];
    const float* b1   = (const float*)d_in[21];
    const float* W2   = (const float*)d_in[22];
    const float* b2   = (const float*)d_in[23];
    float* out = (float*)d_out;

    const long MEG = 1024l * 1024l;
    u16* ws0  = (u16*)d_ws;
    u16* hbuf = ws0 + 0 * MEG;
    u16* qkv  = ws0 + 8 * MEG;            // self: [8192][3072]
    u16* qbuf = ws0 + 8 * MEG;            // cross: [8192][1024]
    u16* kv   = ws0 + 16 * MEG;           // cross: [8192][2048]
    u16* vTb  = ws0 + 32 * MEG;
    u16* encb = ws0 + 32 * MEG;           // dead before vTb is written
    u16* wT   = ws0 + 40 * MEG;           // 3 contiguous MEG: q|k|v transposed
    u16* wT3  = ws0 + 43 * MEG;
    float* x1 = (float*)(ws0 + 44 * MEG); // 8M f32
    u16* ff1  = qkv;                      // 8-40 MEG after attention buffers die
    u16* w1T  = ws0 + 44 * MEG;           // after x1 dies
    u16* w2T  = ws0 + 48 * MEG;

    dim3 blk(256);
    dim3 blk5(512);
    dim3 gW4(16, 16, 4);      // batched 4x 1024^2 weight transpose
    dim3 gA(16, 16, 8);       // attention / batched v-transpose

    // ---- self attention ----
    transpose_w4<<<gW4, blk, 0, stream>>>(Wq_s, Wk_s, Wv_s, Wo_s, wT);  // wT3=wT+3M
    ln_kernel<<<8192, blk, 0, stream>>>(x, ln1g, ln1b, hbuf);
    gemm256<0,0,0,0,0><<<384, blk5, 0, stream>>>(hbuf, wT, nullptr, nullptr, qkv, 32, 1024, 3072);
    transpose_b<<<gA, blk, 0, stream>>>(qkv + 2048, vTb, 1024, 1024, 3072, 1024l * 3072, MEG);
    attn_kernel<true><<<gA, blk, 0, stream>>>(qkv, qkv + 1024, vTb, hbuf, 3072, 3072);
    gemm256<1,1,0,1,0><<<128, blk5, 0, stream>>>(hbuf, wT3, bo_s, x, x1, 32, 1024, 1024);

    // ---- cross attention ----
    transpose_w4<<<gW4, blk, 0, stream>>>(Wq_c, Wk_c, Wv_c, Wo_c, wT);
    ln_kernel<<<8192, blk, 0, stream>>>(x1, ln2g, ln2b, hbuf);
    convert_f32_bf16<<<8192, blk, 0, stream>>>(enc, encb);
    gemm256_cross<<<384, blk5, 0, stream>>>(hbuf, encb, wT, qbuf, kv);
    transpose_b<<<gA, blk, 0, stream>>>(kv + 1024, vTb, 1024, 1024, 2048, 1024l * 2048, MEG);  // encb dead
    attn_kernel<false><<<gA, blk, 0, stream>>>(qbuf, kv, vTb, hbuf, 1024, 2048);
    gemm256<1,1,0,1,0><<<128, blk5, 0, stream>>>(hbuf, wT3, bo_c, x1, out, 32, 1024, 1024);

    // ---- FFN (x1 dead; w1T/w2T reuse its slot) ----
    transpose_w<<<dim3(64, 16, 1), blk, 0, stream>>>(W1, w1T, 1024, 4096);
    transpose_w<<<dim3(16, 64, 1), blk, 0, stream>>>(W2, w2T, 4096, 1024);
    ln_kernel<<<8192, blk, 0, stream>>>(out, ln3g, ln3b, hbuf);
    gemm256<1,0,1,0,0><<<512, blk5, 0, stream>>>(hbuf, w1T, b1, nullptr, ff1, 32, 1024, 4096);
    // split-K=2: out already holds x2 (residual); z=0 adds b2.
    gemm256<1,0,0,1,1><<<dim3(128, 2), blk5, 0, stream>>>(ff1, w2T, b2, nullptr, out, 32, 4096, 1024);
}

// Round 6
// 712.977 us; speedup vs baseline: 1.1505x; 1.0536x over previous
//
#include <hip/hip_runtime.h>

typedef unsigned short u16;
typedef __attribute__((ext_vector_type(8))) short bf16x8;   // 8 bf16 = 4 VGPRs
typedef __attribute__((ext_vector_type(4))) float f32x4;

__device__ __forceinline__ float bf2f(u16 u) {
    return __uint_as_float(((unsigned)u) << 16);
}
__device__ __forceinline__ u16 f2bf(float f) {          // RNE (outputs)
    unsigned u = __float_as_uint(f);
    u = (u + 0x7fffu + ((u >> 16) & 1u)) >> 16;
    return (u16)u;
}
__device__ __forceinline__ u16 f2bf_fast(float f) {     // RN w/o tie fix (P only)
    return (u16)((__float_as_uint(f) + 0x8000u) >> 16);
}
__device__ __forceinline__ float fexp2(float x) { return __builtin_amdgcn_exp2f(x); }
__device__ __forceinline__ void gld_lds16(const u16* g, u16* l) {
    __builtin_amdgcn_global_load_lds(
        (const __attribute__((address_space(1))) void*)g,
        (__attribute__((address_space(3))) void*)l, 16, 0, 0);
}
__device__ __forceinline__ unsigned lds_off(const u16* p) {
    return (unsigned)(unsigned long long)(const __attribute__((address_space(3))) u16*)p;
}
__device__ __forceinline__ void barrier_() {
    asm volatile("" ::: "memory");
    __builtin_amdgcn_s_barrier();
    asm volatile("" ::: "memory");
}
#define VMCNT(n) asm volatile("s_waitcnt vmcnt(" #n ")" ::: "memory")
#define LGKM(n) do { \
    asm volatile("s_waitcnt lgkmcnt(" #n ")" ::: "memory"); \
    __builtin_amdgcn_sched_barrier(0); \
} while(0)
#define DSR(dst, addr) asm volatile("ds_read_b128 %0, %1" : "=v"(dst) : "v"(addr))

// ---------------------------------------------------------------------------
// convert: f32 -> bf16, 4 elems/thread.
// ---------------------------------------------------------------------------
__global__ __launch_bounds__(256) void convert_f32_bf16(
    const float* __restrict__ in, u16* __restrict__ out) {
    long i = ((long)blockIdx.x * 256 + threadIdx.x) * 4;
    float4 v = *(const float4*)&in[i];
    alignas(8) u16 o[4] = {f2bf(v.x), f2bf(v.y), f2bf(v.z), f2bf(v.w)};
    *(uint2*)&out[i] = *(const uint2*)o;
}

// ---------------------------------------------------------------------------
// Weight transpose + downcast: f32 [R][C] -> bf16 [C][R], 64x64 tiles.
// ---------------------------------------------------------------------------
__device__ __forceinline__ void transpose_w_body(
    const float* __restrict__ in, u16* __restrict__ out, int R, int C) {
    __shared__ u16 tile[64][72];
    int r0 = blockIdx.y * 64, c0 = blockIdx.x * 64;
    int tid = threadIdx.x;
#pragma unroll
    for (int it = 0; it < 4; ++it) {
        int f = it * 1024 + tid * 4;
        int r = f >> 6, c = f & 63;
        float4 v = *(const float4*)&in[(long)(r0 + r) * C + (c0 + c)];
        alignas(8) u16 o[4] = {f2bf(v.x), f2bf(v.y), f2bf(v.z), f2bf(v.w)};
        *(uint2*)&tile[r][c] = *(const uint2*)o;
    }
    __syncthreads();
#pragma unroll
    for (int it = 0; it < 2; ++it) {
        int f = it * 2048 + tid * 8;
        int rr = f >> 6, cc = f & 63;
        alignas(16) u16 tmp[8];
#pragma unroll
        for (int i = 0; i < 8; ++i) tmp[i] = tile[cc + i][rr];
        *(uint4*)&out[(long)(c0 + rr) * R + (r0 + cc)] = *(const uint4*)tmp;
    }
}

__global__ __launch_bounds__(256) void transpose_w(
    const float* __restrict__ in, u16* __restrict__ out, int R, int C) {
    transpose_w_body(in, out, R, C);
}

// 4 batched 1024x1024 transposes (QKVO weights), z selects matrix.
__global__ __launch_bounds__(256) void transpose_w4(
    const float* __restrict__ p0, const float* __restrict__ p1,
    const float* __restrict__ p2, const float* __restrict__ p3,
    u16* __restrict__ out) {
    int z = blockIdx.z;
    const float* in = (z == 0) ? p0 : (z == 1) ? p1 : (z == 2) ? p2 : p3;
    transpose_w_body(in, out + (long)z * 1024 * 1024, 1024, 1024);
}

// ---------------------------------------------------------------------------
// bf16 transpose (for cross V), input row-stride istride, batched via z.
// ---------------------------------------------------------------------------
__global__ __launch_bounds__(256) void transpose_b(
    const u16* __restrict__ in, u16* __restrict__ out,
    int R, int C, int istride, long ibs, long obs) {
    __shared__ u16 tile[64][72];
    const u16* src = in + (long)blockIdx.z * ibs;
    u16* dst = out + (long)blockIdx.z * obs;
    int r0 = blockIdx.y * 64, c0 = blockIdx.x * 64;
    int tid = threadIdx.x;
#pragma unroll
    for (int it = 0; it < 2; ++it) {
        int f = it * 2048 + tid * 8;
        int r = f >> 6, c = f & 63;
        *(uint4*)&tile[r][c] = *(const uint4*)&src[(long)(r0 + r) * istride + (c0 + c)];
    }
    __syncthreads();
#pragma unroll
    for (int it = 0; it < 2; ++it) {
        int f = it * 2048 + tid * 8;
        int rr = f >> 6, cc = f & 63;
        alignas(16) u16 tmp[8];
#pragma unroll
        for (int i = 0; i < 8; ++i) tmp[i] = tile[cc + i][rr];
        *(uint4*)&dst[(long)(c0 + rr) * R + (r0 + cc)] = *(const uint4*)tmp;
    }
}

// ---------------------------------------------------------------------------
// LayerNorm rows of 1024: f32 in, f32 gamma/beta, bf16 out. One block/row.
// ---------------------------------------------------------------------------
__global__ __launch_bounds__(256) void ln_kernel(
    const float* __restrict__ x, const float* __restrict__ g,
    const float* __restrict__ bta, u16* __restrict__ y) {
    long row = blockIdx.x;
    int tid = threadIdx.x;
    float4 v4 = *(const float4*)&x[row * 1024 + tid * 4];
    float v[4] = {v4.x, v4.y, v4.z, v4.w};
    float s = 0.f, ss = 0.f;
#pragma unroll
    for (int i = 0; i < 4; ++i) { s += v[i]; ss += v[i] * v[i]; }
#pragma unroll
    for (int o = 1; o < 64; o <<= 1) { s += __shfl_xor(s, o, 64); ss += __shfl_xor(ss, o, 64); }
    __shared__ float red[8];
    int wv = tid >> 6, lane = tid & 63;
    if (lane == 0) { red[wv] = s; red[4 + wv] = ss; }
    __syncthreads();
    s = red[0] + red[1] + red[2] + red[3];
    ss = red[4] + red[5] + red[6] + red[7];
    float mean = s * (1.f / 1024.f);
    float var = ss * (1.f / 1024.f) - mean * mean;
    float rs = rsqrtf(var + 1e-5f);
    float4 g4 = *(const float4*)&g[tid * 4];
    float4 b4 = *(const float4*)&bta[tid * 4];
    float gg[4] = {g4.x, g4.y, g4.z, g4.w};
    float bb[4] = {b4.x, b4.y, b4.z, b4.w};
    alignas(8) u16 o4[4];
#pragma unroll
    for (int i = 0; i < 4; ++i)
        o4[i] = f2bf((v[i] - mean) * rs * gg[i] + bb[i]);
    *(uint2*)&y[row * 1024 + tid * 4] = *(const uint2*)o4;
}

// ---------------------------------------------------------------------------
// 256xBN 8-phase GEMM (T2+T3+T4+T5). NJ = BN/64 (4 -> 256-wide, 2 -> 128).
// Per-wave output 128 x (NJ*16). Phase: {reads | stage} bar lgkm0 MFMA bar.
// Stage ring: P1 t+1.A(4)  P2 ts2.B(NJ)  P4 vmcnt(NJ)
//             P5 ts2.A(4)  P6 ts3.B(NJ)  P8 vmcnt(NJ)
// Hazards: vmcnt(NJ)@P4 completes t+1.{B,A}, leaves ts2.B flying (lands in
// the B-buffer not read during P5-P8); B LDS reads happen only in P1/P5 and
// are drained (lgkm0+barrier) before the overwriting stage issues.
// LDS swizzle slot^=(row&7): inverse-swizzled global src + swizzled read.
// XCD super-tile map: XCD c=id%8 owns bm-tiles 4c..4c+3; bn walks in groups
// of 4 N-tiles of width bnw=NJ*64. Requires tilesM==32, grid%8==0, tilesN%4==0.
// vtcol>=0: output cols >= vtcol are written TRANSPOSED to vout as
// vout[b][h][d][s] (b=row>>10, s=row&1023, h=(col-vtcol)>>6, d=(col-vtcol)&63)
// -- replaces the separate V transpose pass (bit-identical f2bf values).
// ---------------------------------------------------------------------------
#define STAF(b,t) do { _Pragma("unroll") \
    for (int l = 0; l < 4; ++l) \
        gld_lds16(Ag + (l * 64) * (long)K + (t) * 64, AsL + (b) * 16384 + l * 4096); \
} while(0)
#define STBF(b,t) do { _Pragma("unroll") \
    for (int l = 0; l < NJ; ++l) \
        gld_lds16(Bg + (l * 64) * (long)K + (t) * 64, BsL + (b) * (NJ * 4096) + l * 4096); \
} while(0)
#define RDBX(b) do { _Pragma("unroll") \
    for (int j = 0; j < NJ; ++j) { \
        DSR(bfr[j][0], aB0 + (b) * (NJ * 8192) + j * 2048); \
        DSR(bfr[j][1], aB1 + (b) * (NJ * 8192) + j * 2048); } \
} while(0)
#define RDAX(b,q) do { \
    DSR(a0, aA0 + (b)*32768 + (2*(q)  )*2048); \
    DSR(a1, aA1 + (b)*32768 + (2*(q)  )*2048); \
    DSR(a2, aA0 + (b)*32768 + (2*(q)+1)*2048); \
    DSR(a3, aA1 + (b)*32768 + (2*(q)+1)*2048); \
} while(0)
#define MMX(q) do { \
    __builtin_amdgcn_s_setprio(1); \
    _Pragma("unroll") \
    for (int j = 0; j < NJ; ++j) { \
        acc[2*(q)  ][j] = __builtin_amdgcn_mfma_f32_16x16x32_bf16(a0, bfr[j][0], acc[2*(q)  ][j], 0, 0, 0); \
        acc[2*(q)  ][j] = __builtin_amdgcn_mfma_f32_16x16x32_bf16(a1, bfr[j][1], acc[2*(q)  ][j], 0, 0, 0); \
        acc[2*(q)+1][j] = __builtin_amdgcn_mfma_f32_16x16x32_bf16(a2, bfr[j][0], acc[2*(q)+1][j], 0, 0, 0); \
        acc[2*(q)+1][j] = __builtin_amdgcn_mfma_f32_16x16x32_bf16(a3, bfr[j][1], acc[2*(q)+1][j], 0, 0, 0); } \
    __builtin_amdgcn_s_setprio(0); \
} while(0)
#define VMCNTNJ() do { if constexpr (NJ == 4) { VMCNT(4); } else { VMCNT(2); } } while(0)

// XCD-pinned 4x4 super-tile block mapping. tilesM==32 (M=8192, BM=256);
// bnw = N-tile width in elements (NJ*64). bn tile index = k*4 + (off>>2).
__device__ __forceinline__ void supertile_map(int id, int bnw, long& bm, long& bn) {
    int c = id & 7, j = id >> 3;
    int k = j >> 4, off = j & 15;
    bm = (long)(c * 4 + (off & 3)) * 256;
    bn = (long)(k * 4 + (off >> 2)) * bnw;
}

template<int NJ, int BIAS, int RES, int RELU, int OUTF32>
__device__ __forceinline__ void gemm_body(
    const u16* __restrict__ A, const u16* __restrict__ Bt,
    const float* __restrict__ bias, const float* __restrict__ res,
    void* __restrict__ Cv, long bm, long bn, int K, int ldc,
    int vtcol, u16* __restrict__ vout, u16* As, u16* Bs) {
    int tid = threadIdx.x;
    int lane = tid & 63;
    int l15 = lane & 15, quad = lane >> 4;
    int wv = tid >> 6, wm = wv >> 2, wn = wv & 3;
    int NT = K >> 6, NI = NT >> 1;

    // staging addresses (linear LDS dest, inverse-swizzled global source)
    int srow = tid >> 3;                                // 0..63
    int scol = ((tid & 7) ^ (srow & 7)) << 3;           // u16 elems
    const u16* Ag = A + (bm + srow) * (long)K + scol;
    const u16* Bg = Bt + (bn + srow) * (long)K + scol;
    u16* AsL = As + tid * 8;
    u16* BsL = Bs + tid * 8;

    // fragment read addresses (swizzled), 32-bit LDS byte addresses
    int c0 = (quad * 8) ^ ((l15 & 7) << 3);
    int c1 = (32 + quad * 8) ^ ((l15 & 7) << 3);
    unsigned arB = lds_off(As + (wm * 128 + l15) * 64);
    unsigned brB = lds_off(Bs + (wn * (NJ * 16) + l15) * 64);
    unsigned aA0 = arB + 2 * c0, aA1 = arB + 2 * c1;
    unsigned aB0 = brB + 2 * c0, aB1 = brB + 2 * c1;

    f32x4 zf = {0.f, 0.f, 0.f, 0.f};
    f32x4 acc[8][NJ];
#pragma unroll
    for (int i = 0; i < 8; ++i)
#pragma unroll
        for (int j = 0; j < NJ; ++j) acc[i][j] = zf;

    // prologue: t0.{A,B} + t1.B; vmcnt(NJ) lands t0, t1.B flies.
    STAF(0,0); STBF(0,0); STBF(1,1);
    VMCNTNJ();
    barrier_();

    bf16x8 bfr[NJ][2];
    bf16x8 a0, a1, a2, a3;

#pragma unroll 1
    for (int it2 = 0; it2 < NI; ++it2) {
        int t = 2 * it2, t1 = t + 1;
        int ts2 = (t + 2 < NT) ? t + 2 : t;       // even -> buf0
        int ts3 = (t + 3 < NT) ? t + 3 : t1;      // odd  -> buf1
        // ---- tile t (buf0) ----
        RDBX(0); RDAX(0,0); STAF(1,t1);
            barrier_(); LGKM(0); MMX(0); barrier_();
        RDAX(0,1); STBF(0,ts2);
            barrier_(); LGKM(0); MMX(1); barrier_();
        RDAX(0,2);
            barrier_(); LGKM(0); MMX(2); barrier_();
        RDAX(0,3); VMCNTNJ();
            barrier_(); LGKM(0); MMX(3); barrier_();
        // ---- tile t+1 (buf1) ----
        RDBX(1); RDAX(1,0); STAF(0,ts2);
            barrier_(); LGKM(0); MMX(0); barrier_();
        RDAX(1,1); STBF(1,ts3);
            barrier_(); LGKM(0); MMX(1); barrier_();
        RDAX(1,2);
            barrier_(); LGKM(0); MMX(2); barrier_();
        RDAX(1,3); VMCNTNJ();
            barrier_(); LGKM(0); MMX(3); barrier_();
    }
    VMCNT(0);   // drain in-flight LDS DMA before workgroup exit

    // epilogue
    long row0 = bm + wm * 128 + quad * 4;
    long col0 = bn + wn * (NJ * 16) + l15;
#pragma unroll
    for (int i = 0; i < 8; ++i) {
        long row = row0 + i * 16;
#pragma unroll
        for (int j = 0; j < NJ; ++j) {
            long col = col0 + j * 16;
            if (vtcol >= 0 && col >= vtcol) {
                // transposed V write: vout[b][h][d][s..s+3]
                long vcol = col - vtcol;
                int hh = (int)(vcol >> 6), d = (int)(vcol & 63);
                int bb = (int)(row >> 10), s = (int)(row & 1023);
                alignas(8) u16 o4[4];
#pragma unroll
                for (int r = 0; r < 4; ++r) o4[r] = f2bf(acc[i][j][r]);
                *(uint2*)(vout + (((long)(bb * 16 + hh) * 64 + d) << 10) + s) =
                    *(const uint2*)o4;
            } else {
                float bv = BIAS ? bias[col] : 0.f;
#pragma unroll
                for (int r = 0; r < 4; ++r) {
                    float v = acc[i][j][r] + bv;
                    if (RES) v += res[(row + r) * ldc + col];
                    if (RELU) v = fmaxf(v, 0.f);
                    if (OUTF32) ((float*)Cv)[(row + r) * ldc + col] = v;
                    else ((u16*)Cv)[(row + r) * ldc + col] = f2bf(v);
                }
            }
        }
    }
}

template<int NJ, int BIAS, int RES, int RELU, int OUTF32>
__global__ __launch_bounds__(512) void gemm_k(
    const u16* __restrict__ A, const u16* __restrict__ Bt,
    const float* __restrict__ bias, const float* __restrict__ res,
    void* __restrict__ Cv, int K, int ldc, int vtcol, u16* __restrict__ vout) {
    __shared__ u16 As[2 * 16384];
    __shared__ u16 Bs[2 * NJ * 4096];
    long bm, bn;
    supertile_map(blockIdx.x, NJ * 64, bm, bn);
    gemm_body<NJ, BIAS, RES, RELU, OUTF32>(
        A, Bt, bias, res, Cv, bm, bn, K, ldc, vtcol, vout, As, Bs);
}

// Merged cross-attention projections, one 384-block dispatch:
//   id <  128: qbuf[8192,1024] = hq @ wT[0]^T
//   id >= 128: kv [8192,2048] = encb @ wT[1..2]^T
__global__ __launch_bounds__(512) void gemm_cross(
    const u16* __restrict__ hq, const u16* __restrict__ encb,
    const u16* __restrict__ wT, u16* __restrict__ qbuf, u16* __restrict__ kv) {
    __shared__ u16 As[2 * 16384];
    __shared__ u16 Bs[2 * 16384];
    int id = blockIdx.x;
    const u16* A; const u16* Bt; u16* C; int ldc;
    if (id < 128) { A = hq; Bt = wT; C = qbuf; ldc = 1024; }
    else { id -= 128; A = encb; Bt = wT + 1024l * 1024l; C = kv; ldc = 2048; }
    long bm, bn;
    supertile_map(id, 256, bm, bn);
    gemm_body<4, 0, 0, 0, 0>(
        A, Bt, nullptr, nullptr, C, bm, bn, 1024, ldc, -1, nullptr, As, Bs);
}

// ---------------------------------------------------------------------------
// Flash attention (bf16). Grid (T/64, H, B); 4 waves x 16 Q rows.
// q/k row strides qld/kld (fused-QKV layouts); vT: [B][H][64][S]; out ld 1024.
// ---------------------------------------------------------------------------
template<bool CAUSAL>
__global__ __launch_bounds__(256) void attn_kernel(
    const u16* __restrict__ q, const u16* __restrict__ k,
    const u16* __restrict__ vT, u16* __restrict__ out, int qld, int kld) {
    __shared__ u16 Qs[64][72];
    __shared__ u16 Ks[64][72];
    __shared__ u16 VTs[64][72];
    __shared__ u16 Ps[4][16][72];
    const int S_ = 1024;
    int qt = CAUSAL ? (gridDim.x - 1 - blockIdx.x) : blockIdx.x;
    int h = blockIdx.y, b = blockIdx.z;
    int tid = threadIdx.x, lane = tid & 63, wv = tid >> 6;
    int l15 = lane & 15, quad = lane >> 4;
    long qbase = ((long)b * 1024 + qt * 64) * qld + h * 64;
    long obase = ((long)b * 1024 + qt * 64) * 1024 + h * 64;
#pragma unroll
    for (int it = 0; it < 2; ++it) {
        int f = it * 2048 + tid * 8;
        int r = f >> 6, c = f & 63;
        *(uint4*)&Qs[r][c] = *(const uint4*)&q[qbase + (long)r * qld + c];
    }
    __syncthreads();
    bf16x8 a0 = *(const bf16x8*)&Qs[wv * 16 + l15][quad * 8];
    bf16x8 a1 = *(const bf16x8*)&Qs[wv * 16 + l15][quad * 8 + 32];
    f32x4 zf = {0.f, 0.f, 0.f, 0.f};
    f32x4 O[4];
#pragma unroll
    for (int j = 0; j < 4; ++j) O[j] = zf;
    const float cs = 0.125f * 1.44269504089f;   // fold 1/sqrt(64) into exp2
    float m_run = -3e30f;                       // wave-shared (16 rows)
    float lp[4] = {0.f, 0.f, 0.f, 0.f};        // per-lane partial l
    long kbase = (long)b * 1024 * kld + h * 64;
    long vtbase = ((long)b * 16 + h) * 64 * (long)S_;
    int ktmax = CAUSAL ? qt : (S_ / 64 - 1);

    for (int kt = 0; kt <= ktmax; ++kt) {
        __syncthreads();
#pragma unroll
        for (int it = 0; it < 2; ++it) {
            int f = it * 2048 + tid * 8;
            int r = f >> 6, c = f & 63;
            *(uint4*)&Ks[r][c]  = *(const uint4*)&k[kbase + (long)(kt * 64 + r) * kld + c];
            *(uint4*)&VTs[r][c] = *(const uint4*)&vT[vtbase + (long)r * S_ + kt * 64 + c];
        }
        __syncthreads();

        f32x4 s[4];
#pragma unroll
        for (int j = 0; j < 4; ++j) {
            bf16x8 kb0 = *(const bf16x8*)&Ks[j * 16 + l15][quad * 8];
            bf16x8 kb1 = *(const bf16x8*)&Ks[j * 16 + l15][quad * 8 + 32];
            f32x4 z = zf;
            z = __builtin_amdgcn_mfma_f32_16x16x32_bf16(a0, kb0, z, 0, 0, 0);
            z = __builtin_amdgcn_mfma_f32_16x16x32_bf16(a1, kb1, z, 0, 0, 0);
            s[j] = z;
        }
        if (CAUSAL && kt == qt) {
#pragma unroll
            for (int j = 0; j < 4; ++j)
#pragma unroll
                for (int r = 0; r < 4; ++r)
                    if ((j * 16 + l15) > (wv * 16 + quad * 4 + r)) s[j][r] = -3e30f;
        }
        float mx = s[0][0];
#pragma unroll
        for (int j = 0; j < 4; ++j)
#pragma unroll
            for (int r = 0; r < 4; ++r) mx = fmaxf(mx, s[j][r]);
#pragma unroll
        for (int o = 1; o < 64; o <<= 1) mx = fmaxf(mx, __shfl_xor(mx, o, 64));
        float mn = fmaxf(m_run, mx);
        bool grew = mn > m_run;
        if (grew) {
            float alpha = fexp2((m_run - mn) * cs);
            m_run = mn;
#pragma unroll
            for (int j = 0; j < 4; ++j) {
                O[j][0] *= alpha; O[j][1] *= alpha; O[j][2] *= alpha; O[j][3] *= alpha;
            }
#pragma unroll
            for (int r = 0; r < 4; ++r) lp[r] *= alpha;
        }
        float mc = m_run * cs;
#pragma unroll
        for (int j = 0; j < 4; ++j)
#pragma unroll
            for (int r = 0; r < 4; ++r) {
                float p = fexp2(__builtin_fmaf(s[j][r], cs, -mc));
                lp[r] += p;
                Ps[wv][quad * 4 + r][j * 16 + l15] = f2bf_fast(p);
            }
        bf16x8 pa0 = *(const bf16x8*)&Ps[wv][l15][quad * 8];
        bf16x8 pa1 = *(const bf16x8*)&Ps[wv][l15][quad * 8 + 32];
#pragma unroll
        for (int j = 0; j < 4; ++j) {
            bf16x8 vb0 = *(const bf16x8*)&VTs[j * 16 + l15][quad * 8];
            bf16x8 vb1 = *(const bf16x8*)&VTs[j * 16 + l15][quad * 8 + 32];
            f32x4 o = O[j];
            o = __builtin_amdgcn_mfma_f32_16x16x32_bf16(pa0, vb0, o, 0, 0, 0);
            o = __builtin_amdgcn_mfma_f32_16x16x32_bf16(pa1, vb1, o, 0, 0, 0);
            O[j] = o;
        }
    }
#pragma unroll
    for (int r = 0; r < 4; ++r) {
#pragma unroll
        for (int o = 1; o < 16; o <<= 1) lp[r] += __shfl_xor(lp[r], o, 64);
        lp[r] = 1.f / lp[r];
    }
#pragma unroll
    for (int j = 0; j < 4; ++j)
#pragma unroll
        for (int r = 0; r < 4; ++r)
            out[obase + (long)(wv * 16 + quad * 4 + r) * 1024 + j * 16 + l15] =
                f2bf(O[j][r] * lp[r]);
}

// ---------------------------------------------------------------------------
// Workspace (u16 units; MEG = 1M; total 60 MEG = 120 MB):
//   0- 8 hbuf | 8-32 qkv (self) / cross: qbuf(8-16)+kv(16-32)
//  32-40 vTb / encb (encb alive only during cross-qkv; self V^T fused into
//        QKV GEMM lands in 32-40 before encb exists; cross V^T uses
//        transpose_b after encb dies)
//  40-43 wT (q|k|v transposed, contiguous) | 43-44 wT3 (o)
//  44-60 x1 (f32); FFN: w1T 44-48, w2T 48-52 (x1 dead), ff1 8-40
//  FFN2: no split-K; res-read of out (x2) replaces atomics.
// ---------------------------------------------------------------------------
extern "C" void kernel_launch(void* const* d_in, const int* in_sizes, int n_in,
                              void* d_out, int out_size, void* d_ws, size_t ws_size,
                              hipStream_t stream) {
    (void)in_sizes; (void)n_in; (void)out_size; (void)ws_size;
    const float* x    = (const float*)d_in[0];
    const float* enc  = (const float*)d_in[1];
    // d_in[2]=tgt_mask, d_in[3]=src_mask: all-true; causal applied explicitly
    const float* ln1g = (const float*)d_in[4];
    const float* ln1b = (const float*)d_in[5];
    const float* ln2g = (const float*)d_in[6];
    const float* ln2b = (const float*)d_in[7];
    const float* ln3g = (const float*)d_in[8];
    const float* ln3b = (const float*)d_in[9];
    const float* Wq_s = (const float*)d_in[10];
    const float* Wk_s = (const float*)d_in[11];
    const float* Wv_s = (const float*)d_in[12];
    const float* Wo_s = (const float*)d_in[13];
    const float* bo_s = (const float*)d_in[14];
    const float* Wq_c = (const float*)d_in[15];
    const float* Wk_c = (const float*)d_in[16];
    const float* Wv_c = (const float*)d_in[17];
    const float* Wo_c = (const float*)d_in[18];
    const float* bo_c = (const float*)d_in[19];
    const float* W1   = (const float*)d_in[20];
    const float* b1   = (const float*)d_in[21];
    const float* W2   = (const float*)d_in[22];
    const float* b2   = (const float*)d_in[23];
    float* out = (float*)d_out;

    const long MEG = 1024l * 1024l;
    u16* ws0  = (u16*)d_ws;
    u16* hbuf = ws0 + 0 * MEG;
    u16* qkv  = ws0 + 8 * MEG;            // self: [8192][3072] (V cols unused)
    u16* qbuf = ws0 + 8 * MEG;            // cross: [8192][1024]
    u16* kv   = ws0 + 16 * MEG;           // cross: [8192][2048]
    u16* vTb  = ws0 + 32 * MEG;
    u16* encb = ws0 + 32 * MEG;           // alive only during cross-qkv
    u16* wT   = ws0 + 40 * MEG;           // 3 contiguous MEG: q|k|v transposed
    u16* wT3  = ws0 + 43 * MEG;
    float* x1 = (float*)(ws0 + 44 * MEG); // 8M f32
    u16* ff1  = qkv;                      // 8-40 MEG after attention buffers die
    u16* w1T  = ws0 + 44 * MEG;           // after x1 dies
    u16* w2T  = ws0 + 48 * MEG;

    dim3 blk(256);
    dim3 blk5(512);
    dim3 gW4(16, 16, 4);      // batched 4x 1024^2 weight transpose
    dim3 gA(16, 16, 8);       // attention / batched v-transpose

    // ---- self attention ----
    transpose_w4<<<gW4, blk, 0, stream>>>(Wq_s, Wk_s, Wv_s, Wo_s, wT);  // wT3=wT+3M
    ln_kernel<<<8192, blk, 0, stream>>>(x, ln1g, ln1b, hbuf);
    // QKV with fused V^T epilogue (cols >= 2048 -> vTb transposed)
    gemm_k<4,0,0,0,0><<<384, blk5, 0, stream>>>(hbuf, wT, nullptr, nullptr, qkv, 1024, 3072, 2048, vTb);
    attn_kernel<true><<<gA, blk, 0, stream>>>(qkv, qkv + 1024, vTb, hbuf, 3072, 3072);
    gemm_k<2,1,1,0,1><<<256, blk5, 0, stream>>>(hbuf, wT3, bo_s, x, x1, 1024, 1024, -1, nullptr);

    // ---- cross attention ----
    transpose_w4<<<gW4, blk, 0, stream>>>(Wq_c, Wk_c, Wv_c, Wo_c, wT);
    ln_kernel<<<8192, blk, 0, stream>>>(x1, ln2g, ln2b, hbuf);
    convert_f32_bf16<<<8192, blk, 0, stream>>>(enc, encb);
    gemm_cross<<<384, blk5, 0, stream>>>(hbuf, encb, wT, qbuf, kv);
    transpose_b<<<gA, blk, 0, stream>>>(kv + 1024, vTb, 1024, 1024, 2048, 1024l * 2048, MEG);  // encb dead
    attn_kernel<false><<<gA, blk, 0, stream>>>(qbuf, kv, vTb, hbuf, 1024, 2048);
    gemm_k<2,1,1,0,1><<<256, blk5, 0, stream>>>(hbuf, wT3, bo_c, x1, out, 1024, 1024, -1, nullptr);

    // ---- FFN (x1 dead; w1T/w2T reuse its slot) ----
    transpose_w<<<dim3(64, 16, 1), blk, 0, stream>>>(W1, w1T, 1024, 4096);
    transpose_w<<<dim3(16, 64, 1), blk, 0, stream>>>(W2, w2T, 4096, 1024);
    ln_kernel<<<8192, blk, 0, stream>>>(out, ln3g, ln3b, hbuf);
    gemm_k<4,1,0,1,0><<<512, blk5, 0, stream>>>(hbuf, w1T, b1, nullptr, ff1, 1024, 4096, -1, nullptr);
    // FFN2: full-K (4096), res = out (x2), no atomics.
    gemm_k<2,1,1,0,1><<<256, blk5, 0, stream>>>(ff1, w2T, b2, out, out, 4096, 1024, -1, nullptr);
}